// Round 1
// baseline (3114.079 us; speedup 1.0000x reference)
//
#include <hip/hip_runtime.h>

// Order-preserving map float -> uint so unsigned atomicMax == float max.
// memset(0) is the identity (0 < encode(x) for all finite/inf x).
__device__ __forceinline__ unsigned ford(float f) {
  unsigned u = __float_as_uint(f);
  return (u & 0x80000000u) ? ~u : (u | 0x80000000u);
}
__device__ __forceinline__ float forddec(unsigned u) {
  return __uint_as_float((u & 0x80000000u) ? (u & 0x7fffffffu) : ~u);
}

// q,k,v = h_x @ W{q,k,v} + b.  One wave per node row: lane j computes col j.
__global__ void qkv_kernel(const float* __restrict__ hx,
                           const float* __restrict__ Wq, const float* __restrict__ bq,
                           const float* __restrict__ Wk, const float* __restrict__ bk,
                           const float* __restrict__ Wv, const float* __restrict__ bv,
                           float* __restrict__ q, float* __restrict__ k,
                           float* __restrict__ v, int n) {
  int gid = blockIdx.x * blockDim.x + threadIdx.x;
  int i = gid >> 6, j = gid & 63;
  if (i >= n) return;
  const float* x = hx + (size_t)i * 64;
  float aq = bq[j], ak = bk[j], av = bv[j];
#pragma unroll
  for (int d = 0; d < 64; ++d) {
    float xv = x[d];  // wave-broadcast load, L1-hit
    aq = fmaf(xv, Wq[d * 64 + j], aq);
    ak = fmaf(xv, Wk[d * 64 + j], ak);
    av = fmaf(xv, Wv[d * 64 + j], av);
  }
  size_t o = (size_t)i * 64 + j;
  q[o] = aq; k[o] = ak; v[o] = av;
}

// Per-edge fused: elin = h_e@We+be ; scores = (q[row]*k[col]).sum_d/sqrt(8) * sum_d(elin)
// ; oe = (scores*elin)@Woe+boe ; atomicMax segment max of gated scores.
// One wave per edge. Lane j = flat index d*8+h (h = j&7).
__global__ void edge_kernel(const float* __restrict__ he,
                            const int* __restrict__ row, const int* __restrict__ col,
                            const float* __restrict__ q, const float* __restrict__ k,
                            const float* __restrict__ We, const float* __restrict__ be,
                            const float* __restrict__ Woe, const float* __restrict__ boe,
                            float* __restrict__ oe, float* __restrict__ scores,
                            unsigned* __restrict__ mx, int E) {
  int gid = blockIdx.x * blockDim.x + threadIdx.x;
  int e = gid >> 6, lane = threadIdx.x & 63;
  if (e >= E) return;
  int r = row[e], c = col[e];
  const float* herow = he + (size_t)e * 64;
  float acc = be[lane];
#pragma unroll
  for (int d = 0; d < 64; ++d) acc = fmaf(herow[d], We[d * 64 + lane], acc);
  // per-head dot of q[row], k[col]: lanes {h, h+8, ..., h+56} hold head h partials
  float p = q[(size_t)r * 64 + lane] * k[(size_t)c * 64 + lane];
  float eg = acc;
#pragma unroll
  for (int off = 8; off < 64; off <<= 1) {
    p  += __shfl_xor(p, off, 64);
    eg += __shfl_xor(eg, off, 64);
  }
  float s = p * 0.35355339059327373f * eg;  // gated score for head (lane&7), in all lanes
  if (lane < 8) {
    scores[(size_t)e * 8 + lane] = s;
    atomicMax(&mx[(size_t)r * 8 + lane], ford(s));
  }
  // oe_feat[lane] = s * elin[lane]; 64x64 matvec via readlane broadcasts
  float feat = s * acc;
  float o = boe[lane];
#pragma unroll
  for (int d = 0; d < 64; ++d)
    o = fmaf(__shfl(feat, d, 64), Woe[d * 64 + lane], o);
  oe[(size_t)e * 64 + lane] = o;
}

// den[r,h] = sum_{e: row[e]=r} exp(scores[e,h] - mx[r,h])
__global__ void den_kernel(const float* __restrict__ scores,
                           const int* __restrict__ row, const unsigned* __restrict__ mx,
                           float* __restrict__ den, int E) {
  int gid = blockIdx.x * blockDim.x + threadIdx.x;
  if (gid >= E * 8) return;
  int e = gid >> 3, h = gid & 7;
  int r = row[e];
  float m = forddec(mx[r * 8 + h]);
  atomicAdd(&den[r * 8 + h], __expf(scores[gid] - m));
}

// h_out[row] += softmax_weight * v[col].  One wave per edge, lane j = d*8+h.
__global__ void spmm_kernel(const float* __restrict__ scores,
                            const int* __restrict__ row, const int* __restrict__ col,
                            const unsigned* __restrict__ mx, const float* __restrict__ den,
                            const float* __restrict__ v, float* __restrict__ hout, int E) {
  int gid = blockIdx.x * blockDim.x + threadIdx.x;
  int e = gid >> 6, lane = threadIdx.x & 63;
  if (e >= E) return;
  int r = row[e], c = col[e], h = lane & 7;
  float m = forddec(mx[r * 8 + h]);
  float dn = den[r * 8 + h];
  float sm = __expf(scores[(size_t)e * 8 + h] - m) / dn;
  atomicAdd(&hout[(size_t)r * 64 + lane], sm * v[(size_t)c * 64 + lane]);
}

// y = x @ W + b  (one wave per row)
__global__ void out_lin_kernel(const float* __restrict__ xin,
                               const float* __restrict__ W, const float* __restrict__ b,
                               float* __restrict__ y, int n) {
  int gid = blockIdx.x * blockDim.x + threadIdx.x;
  int i = gid >> 6, j = gid & 63;
  if (i >= n) return;
  const float* x = xin + (size_t)i * 64;
  float a = b[j];
#pragma unroll
  for (int d = 0; d < 64; ++d) a = fmaf(x[d], W[d * 64 + j], a);
  y[(size_t)i * 64 + j] = a;
}

extern "C" void kernel_launch(void* const* d_in, const int* in_sizes, int n_in,
                              void* d_out, int out_size, void* d_ws, size_t ws_size,
                              hipStream_t stream) {
  const float* hx  = (const float*)d_in[0];
  const float* he  = (const float*)d_in[1];
  const int*   row = (const int*)d_in[2];
  const int*   col = (const int*)d_in[3];
  const float* Wq = (const float*)d_in[4],  *bq = (const float*)d_in[5];
  const float* Wk = (const float*)d_in[6],  *bk = (const float*)d_in[7];
  const float* Wv = (const float*)d_in[8],  *bv = (const float*)d_in[9];
  const float* We = (const float*)d_in[10], *be = (const float*)d_in[11];
  const float* Woh = (const float*)d_in[12], *boh = (const float*)d_in[13];
  const float* Woe = (const float*)d_in[14], *boe = (const float*)d_in[15];

  const int n = in_sizes[0] / 64;
  const int E = in_sizes[2];

  float* out = (float*)d_out;
  float* oh = out;                     // n*64
  float* oe = out + (size_t)n * 64;    // E*64

  // workspace layout (floats): q, k, v (n*64 each) | scores (E*8) | mx (n*8 uint)
  // | den (n*8) | hout (n*64)   => total 3*n*64 + E*8 + 2*n*8 + n*64 floats
  float* ws = (float*)d_ws;
  float*    q      = ws;
  float*    k      = q + (size_t)n * 64;
  float*    v      = k + (size_t)n * 64;
  float*    scores = v + (size_t)n * 64;
  unsigned* mx     = (unsigned*)(scores + (size_t)E * 8);
  float*    den    = (float*)(mx + (size_t)n * 8);
  float*    hout   = den + (size_t)n * 8;

  hipMemsetAsync(mx,   0, (size_t)n * 8 * 4, stream);
  hipMemsetAsync(den,  0, (size_t)n * 8 * 4, stream);
  hipMemsetAsync(hout, 0, (size_t)n * 64 * 4, stream);

  qkv_kernel<<<(n + 3) / 4, 256, 0, stream>>>(hx, Wq, bq, Wk, bk, Wv, bv, q, k, v, n);
  edge_kernel<<<(E + 3) / 4, 256, 0, stream>>>(he, row, col, q, k, We, be, Woe, boe,
                                               oe, scores, mx, E);
  den_kernel<<<(E + 31) / 32, 256, 0, stream>>>(scores, row, mx, den, E);
  spmm_kernel<<<(E + 3) / 4, 256, 0, stream>>>(scores, row, col, mx, den, v, hout, E);
  out_lin_kernel<<<(n + 3) / 4, 256, 0, stream>>>(hout, Woh, boh, oh, n);
}

// Round 2
// 1178.687 us; speedup vs baseline: 2.6420x; 2.6420x over previous
//
#include <hip/hip_runtime.h>

typedef __attribute__((ext_vector_type(8))) short bf16x8;
typedef __attribute__((ext_vector_type(4))) float f32x4;

__device__ __forceinline__ unsigned short f2bf(float f) {
  unsigned u = __float_as_uint(f);
  return (unsigned short)((u + 0x7fffu + ((u >> 16) & 1u)) >> 16);  // RTN
}
__device__ __forceinline__ float bf2f(unsigned short h) {
  return __uint_as_float(((unsigned)h) << 16);
}

// Order-preserving float->uint so unsigned atomicMax == float max; memset(0) = identity.
__device__ __forceinline__ unsigned ford(float f) {
  unsigned u = __float_as_uint(f);
  return (u & 0x80000000u) ? ~u : (u | 0x80000000u);
}
__device__ __forceinline__ float forddec(unsigned u) {
  return __uint_as_float((u & 0x80000000u) ? (u & 0x7fffffffu) : ~u);
}

// out[M,64] = A[M,64] @ W[64,64] + bias.  MFMA 16x16x32 bf16.
// One wave owns a 16-row tile (grid-stride). B-fragments (all of W, bf16) are
// loop-invariant and live in 32 VGPRs; A rows stream from global.
// A-frag: lane l -> A[m0+(l&15)][ (l>>4)*8 + j + 32*kb ], j=0..7
// B-frag: lane l -> W[ (l>>4)*8 + j + 32*kb ][ nb*16 + (l&15) ]
// C/D   : lane l reg r -> row m0+(l>>4)*4+r, col nb*16+(l&15)   [m89/m91-verified]
template<bool IN_BF16, bool OUT_BF16>
__global__ void __launch_bounds__(256) gemm64_kernel(const void* __restrict__ Ain,
    const float* __restrict__ W, const float* __restrict__ bias,
    void* __restrict__ Out, int M) {
  const int tid = threadIdx.x;
  const int l = tid & 63;
  const int g = l >> 4;
  const int n15 = l & 15;

  bf16x8 bfrag[4][2];
  float bv[4];
#pragma unroll
  for (int nb = 0; nb < 4; ++nb) {
    bv[nb] = bias[nb * 16 + n15];
#pragma unroll
    for (int kb = 0; kb < 2; ++kb) {
#pragma unroll
      for (int j = 0; j < 8; ++j)
        bfrag[nb][kb][j] = (short)f2bf(W[(kb * 32 + g * 8 + j) * 64 + nb * 16 + n15]);
    }
  }

  int wid = (blockIdx.x * blockDim.x + tid) >> 6;
  int nw = (gridDim.x * blockDim.x) >> 6;
  int ntiles = (M + 15) >> 4;
  for (int t = wid; t < ntiles; t += nw) {
    int m0 = t << 4;
    int arow = m0 + n15;
    bf16x8 a0, a1;
    if (arow < M) {
      if constexpr (IN_BF16) {
        const unsigned short* ap = (const unsigned short*)Ain + (size_t)arow * 64 + g * 8;
        a0 = *(const bf16x8*)ap;
        a1 = *(const bf16x8*)(ap + 32);
      } else {
        const float* ap = (const float*)Ain + (size_t)arow * 64 + g * 8;
        f32x4 x0 = *(const f32x4*)ap, x1 = *(const f32x4*)(ap + 4);
        f32x4 x2 = *(const f32x4*)(ap + 32), x3 = *(const f32x4*)(ap + 36);
#pragma unroll
        for (int j = 0; j < 4; ++j) {
          a0[j] = (short)f2bf(x0[j]); a0[4 + j] = (short)f2bf(x1[j]);
          a1[j] = (short)f2bf(x2[j]); a1[4 + j] = (short)f2bf(x3[j]);
        }
      }
    } else {
#pragma unroll
      for (int j = 0; j < 8; ++j) { a0[j] = 0; a1[j] = 0; }
    }
    f32x4 acc[4];
#pragma unroll
    for (int nb = 0; nb < 4; ++nb)
#pragma unroll
      for (int r = 0; r < 4; ++r) acc[nb][r] = 0.0f;
#pragma unroll
    for (int nb = 0; nb < 4; ++nb) {
      acc[nb] = __builtin_amdgcn_mfma_f32_16x16x32_bf16(a0, bfrag[nb][0], acc[nb], 0, 0, 0);
      acc[nb] = __builtin_amdgcn_mfma_f32_16x16x32_bf16(a1, bfrag[nb][1], acc[nb], 0, 0, 0);
    }
#pragma unroll
    for (int nb = 0; nb < 4; ++nb) {
#pragma unroll
      for (int r = 0; r < 4; ++r) {
        int orow = m0 + g * 4 + r;
        if (orow < M) {
          float val = acc[nb][r] + bv[nb];
          size_t oidx = (size_t)orow * 64 + nb * 16 + n15;
          if constexpr (OUT_BF16) ((unsigned short*)Out)[oidx] = f2bf(val);
          else                    ((float*)Out)[oidx] = val;
        }
      }
    }
  }
}

// Per-edge: gate = sum_d elin; s = (q[r].k[c])_h/sqrt(8)*gate_h; write scores,
// atomicMax segment max, feat = s*elin written IN PLACE over elin.
__global__ void __launch_bounds__(256) sddmm_kernel(unsigned short* __restrict__ elinfeat,
    const unsigned short* __restrict__ qb, const unsigned short* __restrict__ kbuf,
    const int* __restrict__ row, const int* __restrict__ col,
    float* __restrict__ scores, unsigned* __restrict__ mx, int E) {
  int gid = blockIdx.x * blockDim.x + threadIdx.x;
  int e = gid >> 6, lane = threadIdx.x & 63;
  if (e >= E) return;
  int r = row[e], c = col[e];
  float el = bf2f(elinfeat[(size_t)e * 64 + lane]);
  float p = bf2f(qb[(size_t)r * 64 + lane]) * bf2f(kbuf[(size_t)c * 64 + lane]);
  float eg = el;
#pragma unroll
  for (int off = 8; off < 64; off <<= 1) {
    p  += __shfl_xor(p, off, 64);
    eg += __shfl_xor(eg, off, 64);
  }
  float s = p * 0.35355339059327373f * eg;  // lane holds head h=lane&7
  if (lane < 8) {
    scores[(size_t)e * 8 + lane] = s;
    atomicMax(&mx[(size_t)r * 8 + lane], ford(s));
  }
  elinfeat[(size_t)e * 64 + lane] = f2bf(s * el);
}

__global__ void den_kernel(const float* __restrict__ scores,
                           const int* __restrict__ row, const unsigned* __restrict__ mx,
                           float* __restrict__ den, int E) {
  int gid = blockIdx.x * blockDim.x + threadIdx.x;
  if (gid >= E * 8) return;
  int e = gid >> 3, h = gid & 7;
  int r = row[e];
  float m = forddec(mx[r * 8 + h]);
  atomicAdd(&den[r * 8 + h], __expf(scores[gid] - m));
}

__global__ void __launch_bounds__(256) spmm_kernel(const float* __restrict__ scores,
    const int* __restrict__ row, const int* __restrict__ col,
    const unsigned* __restrict__ mx, const float* __restrict__ den,
    const unsigned short* __restrict__ vb, float* __restrict__ hout, int E) {
  int gid = blockIdx.x * blockDim.x + threadIdx.x;
  int e = gid >> 6, lane = threadIdx.x & 63;
  if (e >= E) return;
  int r = row[e], c = col[e], h = lane & 7;
  float m = forddec(mx[r * 8 + h]);
  float dn = den[r * 8 + h];
  float sm = __expf(scores[(size_t)e * 8 + h] - m) / dn;
  atomicAdd(&hout[(size_t)r * 64 + lane], sm * bf2f(vb[(size_t)c * 64 + lane]));
}

extern "C" void kernel_launch(void* const* d_in, const int* in_sizes, int n_in,
                              void* d_out, int out_size, void* d_ws, size_t ws_size,
                              hipStream_t stream) {
  const float* hx  = (const float*)d_in[0];
  const float* he  = (const float*)d_in[1];
  const int*   row = (const int*)d_in[2];
  const int*   col = (const int*)d_in[3];
  const float* Wq = (const float*)d_in[4],  *bq = (const float*)d_in[5];
  const float* Wk = (const float*)d_in[6],  *bk = (const float*)d_in[7];
  const float* Wv = (const float*)d_in[8],  *bv = (const float*)d_in[9];
  const float* We = (const float*)d_in[10], *be = (const float*)d_in[11];
  const float* Woh = (const float*)d_in[12], *boh = (const float*)d_in[13];
  const float* Woe = (const float*)d_in[14], *boe = (const float*)d_in[15];

  const int n = in_sizes[0] / 64;
  const int E = in_sizes[2];

  float* out = (float*)d_out;
  float* oh = out;                   // n*64 fp32
  float* oe = out + (size_t)n * 64;  // E*64 fp32

  // ws: qb,kb,vb (n*64 bf16 each) | elin/feat (E*64 bf16, in-place) |
  //     scores (E*8 f32) | mx (n*8 u32) | den (n*8 f32) | hout (n*64 f32)
  unsigned short* qb   = (unsigned short*)d_ws;
  unsigned short* kbuf = qb + (size_t)n * 64;
  unsigned short* vbuf = kbuf + (size_t)n * 64;
  unsigned short* elin = vbuf + (size_t)n * 64;
  float*    scores = (float*)(elin + (size_t)E * 64);
  unsigned* mx     = (unsigned*)(scores + (size_t)E * 8);
  float*    den    = (float*)(mx + (size_t)n * 8);
  float*    hout   = den + (size_t)n * 8;

  hipMemsetAsync(mx,   0, (size_t)n * 8 * 4, stream);
  hipMemsetAsync(den,  0, (size_t)n * 8 * 4, stream);
  hipMemsetAsync(hout, 0, (size_t)n * 64 * 4, stream);

  gemm64_kernel<false, true><<<512, 256, 0, stream>>>(hx, Wq, bq, qb, n);
  gemm64_kernel<false, true><<<512, 256, 0, stream>>>(hx, Wk, bk, kbuf, n);
  gemm64_kernel<false, true><<<512, 256, 0, stream>>>(hx, Wv, bv, vbuf, n);
  gemm64_kernel<false, true><<<2048, 256, 0, stream>>>(he, We, be, elin, E);

  sddmm_kernel<<<(E + 3) / 4, 256, 0, stream>>>(elin, qb, kbuf, row, col, scores, mx, E);
  den_kernel<<<(E * 8 + 255) / 256, 256, 0, stream>>>(scores, row, mx, den, E);

  gemm64_kernel<true, false><<<2048, 256, 0, stream>>>(elin, Woe, boe, oe, E);

  spmm_kernel<<<(E + 3) / 4, 256, 0, stream>>>(scores, row, col, mx, den, vbuf, hout, E);
  gemm64_kernel<false, false><<<512, 256, 0, stream>>>(hout, Woh, boh, oh, n);
}

// Round 3
// 1049.817 us; speedup vs baseline: 2.9663x; 1.1228x over previous
//
#include <hip/hip_runtime.h>

typedef __attribute__((ext_vector_type(8))) short bf16x8;
typedef __attribute__((ext_vector_type(4))) float f32x4;

__device__ __forceinline__ unsigned short f2bf(float f) {
  unsigned u = __float_as_uint(f);
  return (unsigned short)((u + 0x7fffu + ((u >> 16) & 1u)) >> 16);  // RTN
}
__device__ __forceinline__ float bf2f(unsigned short h) {
  return __uint_as_float(((unsigned)h) << 16);
}

// ---------------- GEMM64: out[M,64] = A[M,64] @ W[64,64] + b ----------------
// One wave per 16-row tile (grid-stride); W lives in 32 VGPRs as B-fragments.
// A-frag: lane l -> A[m0+(l&15)][(l>>4)*8+j+32*kb]; C: row=(l>>4)*4+r, col=l&15 (+16*nb)
template<bool IN_BF16, bool OUT_BF16>
__global__ void __launch_bounds__(256) gemm64_kernel(const void* __restrict__ Ain,
    const float* __restrict__ W, const float* __restrict__ bias,
    void* __restrict__ Out, int M) {
  const int tid = threadIdx.x;
  const int l = tid & 63;
  const int g = l >> 4;
  const int n15 = l & 15;

  bf16x8 bfrag[4][2];
  float bv[4];
#pragma unroll
  for (int nb = 0; nb < 4; ++nb) {
    bv[nb] = bias[nb * 16 + n15];
#pragma unroll
    for (int kb = 0; kb < 2; ++kb)
#pragma unroll
      for (int j = 0; j < 8; ++j)
        bfrag[nb][kb][j] = (short)f2bf(W[(kb * 32 + g * 8 + j) * 64 + nb * 16 + n15]);
  }

  int wid = (blockIdx.x * blockDim.x + tid) >> 6;
  int nw = (gridDim.x * blockDim.x) >> 6;
  int ntiles = (M + 15) >> 4;
  for (int t = wid; t < ntiles; t += nw) {
    int m0 = t << 4;
    int arow = m0 + n15;
    bf16x8 a0, a1;
    if (arow < M) {
      if constexpr (IN_BF16) {
        const unsigned short* ap = (const unsigned short*)Ain + (size_t)arow * 64 + g * 8;
        a0 = *(const bf16x8*)ap;
        a1 = *(const bf16x8*)(ap + 32);
      } else {
        const float* ap = (const float*)Ain + (size_t)arow * 64 + g * 8;
        f32x4 x0 = *(const f32x4*)ap, x1 = *(const f32x4*)(ap + 4);
        f32x4 x2 = *(const f32x4*)(ap + 32), x3 = *(const f32x4*)(ap + 36);
#pragma unroll
        for (int j = 0; j < 4; ++j) {
          a0[j] = (short)f2bf(x0[j]); a0[4 + j] = (short)f2bf(x1[j]);
          a1[j] = (short)f2bf(x2[j]); a1[4 + j] = (short)f2bf(x3[j]);
        }
      }
    } else {
#pragma unroll
      for (int j = 0; j < 8; ++j) { a0[j] = 0; a1[j] = 0; }
    }
    f32x4 acc[4];
#pragma unroll
    for (int nb = 0; nb < 4; ++nb)
#pragma unroll
      for (int r = 0; r < 4; ++r) acc[nb][r] = 0.0f;
#pragma unroll
    for (int nb = 0; nb < 4; ++nb) {
      acc[nb] = __builtin_amdgcn_mfma_f32_16x16x32_bf16(a0, bfrag[nb][0], acc[nb], 0, 0, 0);
      acc[nb] = __builtin_amdgcn_mfma_f32_16x16x32_bf16(a1, bfrag[nb][1], acc[nb], 0, 0, 0);
    }
#pragma unroll
    for (int nb = 0; nb < 4; ++nb)
#pragma unroll
      for (int r = 0; r < 4; ++r) {
        int orow = m0 + g * 4 + r;
        if (orow < M) {
          float val = acc[nb][r] + bv[nb];
          size_t oidx = (size_t)orow * 64 + nb * 16 + n15;
          if constexpr (OUT_BF16) ((unsigned short*)Out)[oidx] = f2bf(val);
          else                    ((float*)Out)[oidx] = val;
        }
      }
  }
}

// Fused q/k/v: 3 weight sets resident (96 VGPR), hx read once, bf16 outputs.
__global__ void __launch_bounds__(256) qkv3_kernel(const float* __restrict__ hx,
    const float* __restrict__ Wq, const float* __restrict__ bq,
    const float* __restrict__ Wk, const float* __restrict__ bk,
    const float* __restrict__ Wv, const float* __restrict__ bv,
    unsigned short* __restrict__ q, unsigned short* __restrict__ k,
    unsigned short* __restrict__ v, int M) {
  const int tid = threadIdx.x;
  const int l = tid & 63;
  const int g = l >> 4;
  const int n15 = l & 15;
  const float* Ws[3] = {Wq, Wk, Wv};
  const float* bs[3] = {bq, bk, bv};
  unsigned short* outs[3] = {q, k, v};

  bf16x8 bfrag[3][4][2];
  float bvv[3][4];
#pragma unroll
  for (int w = 0; w < 3; ++w)
#pragma unroll
    for (int nb = 0; nb < 4; ++nb) {
      bvv[w][nb] = bs[w][nb * 16 + n15];
#pragma unroll
      for (int kb = 0; kb < 2; ++kb)
#pragma unroll
        for (int j = 0; j < 8; ++j)
          bfrag[w][nb][kb][j] = (short)f2bf(Ws[w][(kb * 32 + g * 8 + j) * 64 + nb * 16 + n15]);
    }

  int wid = (blockIdx.x * blockDim.x + tid) >> 6;
  int nw = (gridDim.x * blockDim.x) >> 6;
  int ntiles = (M + 15) >> 4;
  for (int t = wid; t < ntiles; t += nw) {
    int m0 = t << 4;
    int arow = m0 + n15;
    bf16x8 a0, a1;
    if (arow < M) {
      const float* ap = hx + (size_t)arow * 64 + g * 8;
      f32x4 x0 = *(const f32x4*)ap, x1 = *(const f32x4*)(ap + 4);
      f32x4 x2 = *(const f32x4*)(ap + 32), x3 = *(const f32x4*)(ap + 36);
#pragma unroll
      for (int j = 0; j < 4; ++j) {
        a0[j] = (short)f2bf(x0[j]); a0[4 + j] = (short)f2bf(x1[j]);
        a1[j] = (short)f2bf(x2[j]); a1[4 + j] = (short)f2bf(x3[j]);
      }
    } else {
#pragma unroll
      for (int j = 0; j < 8; ++j) { a0[j] = 0; a1[j] = 0; }
    }
#pragma unroll
    for (int w = 0; w < 3; ++w) {
      f32x4 acc[4];
#pragma unroll
      for (int nb = 0; nb < 4; ++nb)
#pragma unroll
        for (int r = 0; r < 4; ++r) acc[nb][r] = 0.0f;
#pragma unroll
      for (int nb = 0; nb < 4; ++nb) {
        acc[nb] = __builtin_amdgcn_mfma_f32_16x16x32_bf16(a0, bfrag[w][nb][0], acc[nb], 0, 0, 0);
        acc[nb] = __builtin_amdgcn_mfma_f32_16x16x32_bf16(a1, bfrag[w][nb][1], acc[nb], 0, 0, 0);
      }
#pragma unroll
      for (int nb = 0; nb < 4; ++nb)
#pragma unroll
        for (int r = 0; r < 4; ++r) {
          int orow = m0 + g * 4 + r;
          if (orow < M)
            outs[w][(size_t)orow * 64 + nb * 16 + n15] = f2bf(acc[nb][r] + bvv[w][nb]);
        }
    }
  }
}

// Per-edge: gate=sum(elin); s=(q[r].k[c])_h/sqrt8*gate; write scores; feat=s*elin in place.
__global__ void __launch_bounds__(256) sddmm_kernel(unsigned short* __restrict__ elinfeat,
    const unsigned short* __restrict__ qb, const unsigned short* __restrict__ kbuf,
    const int* __restrict__ row, const int* __restrict__ col,
    float* __restrict__ scores, int E) {
  int gid = blockIdx.x * blockDim.x + threadIdx.x;
  int e = gid >> 6, lane = threadIdx.x & 63;
  if (e >= E) return;
  int r = row[e], c = col[e];
  float el = bf2f(elinfeat[(size_t)e * 64 + lane]);
  float p = bf2f(qb[(size_t)r * 64 + lane]) * bf2f(kbuf[(size_t)c * 64 + lane]);
  float eg = el;
#pragma unroll
  for (int off = 8; off < 64; off <<= 1) {
    p  += __shfl_xor(p, off, 64);
    eg += __shfl_xor(eg, off, 64);
  }
  float s = p * 0.35355339059327373f * eg;
  if (lane < 8) scores[(size_t)e * 8 + lane] = s;
  elinfeat[(size_t)e * 64 + lane] = f2bf(s * el);
}

// ---------------- CSR build ----------------
__global__ void hist_kernel(const int* __restrict__ row, int* __restrict__ deg, int E) {
  int gid = blockIdx.x * blockDim.x + threadIdx.x;
  if (gid < E) atomicAdd(&deg[row[gid]], 1);
}

#define SCAN_B 256
#define SCAN_E 8  // 2048 elems per block
__global__ void scan1_kernel(const int* __restrict__ deg, int* __restrict__ rowptr,
                             int* __restrict__ blksum, int n) {
  __shared__ int sh[SCAN_B];
  int base = blockIdx.x * (SCAN_B * SCAN_E) + threadIdx.x * SCAN_E;
  int v[SCAN_E];
  int s = 0;
#pragma unroll
  for (int j = 0; j < SCAN_E; ++j) {
    v[j] = (base + j < n) ? deg[base + j] : 0;
    s += v[j];
  }
  sh[threadIdx.x] = s;
  __syncthreads();
  for (int off = 1; off < SCAN_B; off <<= 1) {
    int t = (threadIdx.x >= off) ? sh[threadIdx.x - off] : 0;
    __syncthreads();
    sh[threadIdx.x] += t;
    __syncthreads();
  }
  if (threadIdx.x == SCAN_B - 1) blksum[blockIdx.x] = sh[SCAN_B - 1];
  int run = sh[threadIdx.x] - s;  // exclusive prefix for this thread
#pragma unroll
  for (int j = 0; j < SCAN_E; ++j) {
    if (base + j < n) rowptr[base + j] = run;
    run += v[j];
  }
}

__global__ void scan2_kernel(int* __restrict__ blksum, int nb) {
  __shared__ int sh[SCAN_B];
  int v = (threadIdx.x < nb) ? blksum[threadIdx.x] : 0;
  sh[threadIdx.x] = v;
  __syncthreads();
  for (int off = 1; off < SCAN_B; off <<= 1) {
    int t = (threadIdx.x >= off) ? sh[threadIdx.x - off] : 0;
    __syncthreads();
    sh[threadIdx.x] += t;
    __syncthreads();
  }
  if (threadIdx.x < nb) blksum[threadIdx.x] = sh[threadIdx.x] - v;
}

__global__ void scan3_kernel(int* __restrict__ rowptr, int* __restrict__ cursor,
                             const int* __restrict__ blksum, int n) {
  int i = blockIdx.x * blockDim.x + threadIdx.x;
  if (i >= n) return;
  int v = rowptr[i] + blksum[i / (SCAN_B * SCAN_E)];
  rowptr[i] = v;
  cursor[i] = v;
}

__global__ void scatter_kernel(const int* __restrict__ row, const int* __restrict__ col,
                               int* __restrict__ cursor, int* __restrict__ eidx,
                               int* __restrict__ ecol, int E) {
  int gid = blockIdx.x * blockDim.x + threadIdx.x;
  if (gid >= E) return;
  int r = row[gid];
  int slot = atomicAdd(&cursor[r], 1);
  eidx[slot] = gid;
  ecol[slot] = col[gid];
}

// One wave per row: online softmax + weighted-V accumulation, single write.
__global__ void __launch_bounds__(256) row_attn_kernel(const float* __restrict__ scores,
    const int* __restrict__ rowptr, const int* __restrict__ deg,
    const int* __restrict__ eidx, const int* __restrict__ ecol,
    const unsigned short* __restrict__ vb, float* __restrict__ hout, int n) {
  int gid = blockIdx.x * blockDim.x + threadIdx.x;
  int r = gid >> 6, lane = threadIdx.x & 63;
  if (r >= n) return;
  int start = rowptr[r], dg = deg[r];
  int h = lane & 7;
  float m = -3.4e38f, den = 0.f, acc = 0.f;
  for (int i = 0; i < dg; ++i) {
    int eid = eidx[start + i];
    int c = ecol[start + i];
    float s = scores[(size_t)eid * 8 + h];
    float vv = bf2f(vb[(size_t)c * 64 + lane]);
    float mn = fmaxf(m, s);
    float corr = __expf(m - mn);
    float ex = __expf(s - mn);
    den = den * corr + ex;
    acc = acc * corr + ex * vv;
    m = mn;
  }
  hout[(size_t)r * 64 + lane] = (dg > 0) ? acc / den : 0.f;
}

extern "C" void kernel_launch(void* const* d_in, const int* in_sizes, int n_in,
                              void* d_out, int out_size, void* d_ws, size_t ws_size,
                              hipStream_t stream) {
  const float* hx  = (const float*)d_in[0];
  const float* he  = (const float*)d_in[1];
  const int*   row = (const int*)d_in[2];
  const int*   col = (const int*)d_in[3];
  const float* Wq = (const float*)d_in[4],  *bq = (const float*)d_in[5];
  const float* Wk = (const float*)d_in[6],  *bk = (const float*)d_in[7];
  const float* Wv = (const float*)d_in[8],  *bv = (const float*)d_in[9];
  const float* We = (const float*)d_in[10], *be = (const float*)d_in[11];
  const float* Woh = (const float*)d_in[12], *boh = (const float*)d_in[13];
  const float* Woe = (const float*)d_in[14], *boe = (const float*)d_in[15];

  const int n = in_sizes[0] / 64;
  const int E = in_sizes[2];

  float* out = (float*)d_out;
  float* oh = out;                   // n*64 fp32
  float* oe = out + (size_t)n * 64;  // E*64 fp32

  // ws: qb,kb,vb (n*64 bf16) | elin/feat (E*64 bf16 in-place) | scores (E*8 f32)
  //     | hout (n*64 f32).  CSR arrays overlay qb/kb after sddmm (qb,kb dead).
  unsigned short* qb   = (unsigned short*)d_ws;
  unsigned short* kb   = qb + (size_t)n * 64;
  unsigned short* vbuf = kb + (size_t)n * 64;
  unsigned short* elin = vbuf + (size_t)n * 64;
  float* scores = (float*)(elin + (size_t)E * 64);
  float* hout   = scores + (size_t)E * 8;

  int* deg    = (int*)qb;          // n
  int* rowptr = deg + n;           // n
  int* cursor = rowptr + n;        // n
  int* blksum = cursor + n;        // <=256
  int* eidx   = blksum + 256;      // E
  int* ecol   = eidx + (size_t)E;  // E   (fits: 2E+3n+256 ints << 2*n*64 ushorts... uses kb too)

  const int nb_scan = (n + SCAN_B * SCAN_E - 1) / (SCAN_B * SCAN_E);

  qkv3_kernel<<<512, 256, 0, stream>>>(hx, Wq, bq, Wk, bk, Wv, bv, qb, kb, vbuf, n);
  gemm64_kernel<false, true><<<2048, 256, 0, stream>>>(he, We, be, elin, E);
  sddmm_kernel<<<(E + 3) / 4, 256, 0, stream>>>(elin, qb, kb, row, col, scores, E);

  // oe = feat @ Woe + boe (independent of CSR work)
  gemm64_kernel<true, false><<<2048, 256, 0, stream>>>(elin, Woe, boe, oe, E);

  // CSR build (overlays dead qb/kb region)
  hipMemsetAsync(deg, 0, (size_t)n * 4, stream);
  hist_kernel<<<(E + 255) / 256, 256, 0, stream>>>(row, deg, E);
  scan1_kernel<<<nb_scan, SCAN_B, 0, stream>>>(deg, rowptr, blksum, n);
  scan2_kernel<<<1, SCAN_B, 0, stream>>>(blksum, nb_scan);
  scan3_kernel<<<(n + 255) / 256, 256, 0, stream>>>(rowptr, cursor, blksum, n);
  scatter_kernel<<<(E + 255) / 256, 256, 0, stream>>>(row, col, cursor, eidx, ecol, E);

  row_attn_kernel<<<(n + 3) / 4, 256, 0, stream>>>(scores, rowptr, deg, eidx, ecol,
                                                   vbuf, hout, n);
  gemm64_kernel<false, false><<<512, 256, 0, stream>>>(hout, Woh, boh, oh, n);
}

// Round 5
// 640.651 us; speedup vs baseline: 4.8608x; 1.6387x over previous
//
#include <hip/hip_runtime.h>

typedef __attribute__((ext_vector_type(8))) short bf16x8;
typedef __attribute__((ext_vector_type(4))) float f32x4;

__device__ __forceinline__ unsigned short f2bf(float f) {
  unsigned u = __float_as_uint(f);
  return (unsigned short)((u + 0x7fffu + ((u >> 16) & 1u)) >> 16);  // RTN
}
__device__ __forceinline__ float bf2f(unsigned short h) {
  return __uint_as_float(((unsigned)h) << 16);
}

// ---------------- GEMM64: out[M,64] = A[M,64] @ W[64,64] + b ----------------
template<bool IN_BF16, bool OUT_BF16>
__global__ void __launch_bounds__(256) gemm64_kernel(const void* __restrict__ Ain,
    const float* __restrict__ W, const float* __restrict__ bias,
    void* __restrict__ Out, int M) {
  const int tid = threadIdx.x;
  const int l = tid & 63;
  const int g = l >> 4;
  const int n15 = l & 15;

  bf16x8 bfrag[4][2];
  float bv[4];
#pragma unroll
  for (int nb = 0; nb < 4; ++nb) {
    bv[nb] = bias[nb * 16 + n15];
#pragma unroll
    for (int kb = 0; kb < 2; ++kb)
#pragma unroll
      for (int j = 0; j < 8; ++j)
        bfrag[nb][kb][j] = (short)f2bf(W[(kb * 32 + g * 8 + j) * 64 + nb * 16 + n15]);
  }

  int wid = (blockIdx.x * blockDim.x + tid) >> 6;
  int nw = (gridDim.x * blockDim.x) >> 6;
  int ntiles = (M + 15) >> 4;
  for (int t = wid; t < ntiles; t += nw) {
    int m0 = t << 4;
    int arow = m0 + n15;
    bf16x8 a0, a1;
    if (arow < M) {
      if constexpr (IN_BF16) {
        const unsigned short* ap = (const unsigned short*)Ain + (size_t)arow * 64 + g * 8;
        a0 = *(const bf16x8*)ap;
        a1 = *(const bf16x8*)(ap + 32);
      } else {
        const float* ap = (const float*)Ain + (size_t)arow * 64 + g * 8;
        f32x4 x0 = *(const f32x4*)ap, x1 = *(const f32x4*)(ap + 4);
        f32x4 x2 = *(const f32x4*)(ap + 32), x3 = *(const f32x4*)(ap + 36);
#pragma unroll
        for (int j = 0; j < 4; ++j) {
          a0[j] = (short)f2bf(x0[j]); a0[4 + j] = (short)f2bf(x1[j]);
          a1[j] = (short)f2bf(x2[j]); a1[4 + j] = (short)f2bf(x3[j]);
        }
      }
    } else {
#pragma unroll
      for (int j = 0; j < 8; ++j) { a0[j] = 0; a1[j] = 0; }
    }
    f32x4 acc[4];
#pragma unroll
    for (int nb = 0; nb < 4; ++nb) {
      acc[nb] = (f32x4){bv[nb], bv[nb], bv[nb], bv[nb]};
      acc[nb] = __builtin_amdgcn_mfma_f32_16x16x32_bf16(a0, bfrag[nb][0], acc[nb], 0, 0, 0);
      acc[nb] = __builtin_amdgcn_mfma_f32_16x16x32_bf16(a1, bfrag[nb][1], acc[nb], 0, 0, 0);
    }
#pragma unroll
    for (int nb = 0; nb < 4; ++nb)
#pragma unroll
      for (int r = 0; r < 4; ++r) {
        int orow = m0 + g * 4 + r;
        if (orow < M) {
          float val = acc[nb][r];
          size_t oidx = (size_t)orow * 64 + nb * 16 + n15;
          if constexpr (OUT_BF16) ((unsigned short*)Out)[oidx] = f2bf(val);
          else                    ((float*)Out)[oidx] = val;
        }
      }
  }
}

// Fused q/k/v: 3 weight sets resident, hx read once, bf16 outputs.
__global__ void __launch_bounds__(256) qkv3_kernel(const float* __restrict__ hx,
    const float* __restrict__ Wq, const float* __restrict__ bq,
    const float* __restrict__ Wk, const float* __restrict__ bk,
    const float* __restrict__ Wv, const float* __restrict__ bv,
    unsigned short* __restrict__ q, unsigned short* __restrict__ k,
    unsigned short* __restrict__ v, int M) {
  const int tid = threadIdx.x;
  const int l = tid & 63;
  const int g = l >> 4;
  const int n15 = l & 15;
  const float* Ws[3] = {Wq, Wk, Wv};
  const float* bs[3] = {bq, bk, bv};
  unsigned short* outs[3] = {q, k, v};

  bf16x8 bfrag[3][4][2];
  float bvv[3][4];
#pragma unroll
  for (int w = 0; w < 3; ++w)
#pragma unroll
    for (int nb = 0; nb < 4; ++nb) {
      bvv[w][nb] = bs[w][nb * 16 + n15];
#pragma unroll
      for (int kb = 0; kb < 2; ++kb)
#pragma unroll
        for (int j = 0; j < 8; ++j)
          bfrag[w][nb][kb][j] = (short)f2bf(Ws[w][(kb * 32 + g * 8 + j) * 64 + nb * 16 + n15]);
    }

  int wid = (blockIdx.x * blockDim.x + tid) >> 6;
  int nw = (gridDim.x * blockDim.x) >> 6;
  int ntiles = (M + 15) >> 4;
  for (int t = wid; t < ntiles; t += nw) {
    int m0 = t << 4;
    int arow = m0 + n15;
    bf16x8 a0, a1;
    if (arow < M) {
      const float* ap = hx + (size_t)arow * 64 + g * 8;
      f32x4 x0 = *(const f32x4*)ap, x1 = *(const f32x4*)(ap + 4);
      f32x4 x2 = *(const f32x4*)(ap + 32), x3 = *(const f32x4*)(ap + 36);
#pragma unroll
      for (int j = 0; j < 4; ++j) {
        a0[j] = (short)f2bf(x0[j]); a0[4 + j] = (short)f2bf(x1[j]);
        a1[j] = (short)f2bf(x2[j]); a1[4 + j] = (short)f2bf(x3[j]);
      }
    } else {
#pragma unroll
      for (int j = 0; j < 8; ++j) { a0[j] = 0; a1[j] = 0; }
    }
#pragma unroll
    for (int w = 0; w < 3; ++w) {
      f32x4 acc[4];
#pragma unroll
      for (int nb = 0; nb < 4; ++nb) {
        acc[nb] = (f32x4){bvv[w][nb], bvv[w][nb], bvv[w][nb], bvv[w][nb]};
        acc[nb] = __builtin_amdgcn_mfma_f32_16x16x32_bf16(a0, bfrag[w][nb][0], acc[nb], 0, 0, 0);
        acc[nb] = __builtin_amdgcn_mfma_f32_16x16x32_bf16(a1, bfrag[w][nb][1], acc[nb], 0, 0, 0);
      }
#pragma unroll
      for (int nb = 0; nb < 4; ++nb)
#pragma unroll
        for (int r = 0; r < 4; ++r) {
          int orow = m0 + g * 4 + r;
          if (orow < M)
            outs[w][(size_t)orow * 64 + nb * 16 + n15] = f2bf(acc[nb][r]);
        }
    }
  }
}

// ---------------- Fused edge pipeline ----------------
// Per 16-edge tile (one wave):
//   elin = he@We+be (MFMA, fp32 acc)             [C: row=g*4+r, col=nb*16+n15]
//   gate[row,h] = sum_dh elin[row, dh*8+h]  ==  sum_nb acc + shfl_xor(,8)  (PER-HEAD!)
//   p[e,h] = q[row[e]].k[col[e]] per head (tiled, lane=edge n15 x colblock g)
//   s = p/sqrt(8)*gate -> scores[e,h]
//   feat = s*elin -> LDS transpose -> A-frag ; oe = feat@Woe+boe
__global__ void __launch_bounds__(256, 3) edge_fused_kernel(
    const float* __restrict__ he,
    const int* __restrict__ rowi, const int* __restrict__ coli,
    const unsigned short* __restrict__ qb, const unsigned short* __restrict__ kbuf,
    const float* __restrict__ We, const float* __restrict__ be,
    const float* __restrict__ Woe, const float* __restrict__ boe,
    float* __restrict__ oe, float* __restrict__ scores, int E) {
  const int tid = threadIdx.x;
  const int wv = tid >> 6;
  const int l = tid & 63;
  const int g = l >> 4;
  const int n15 = l & 15;
  const int h = n15 & 7;

  __shared__ float s_lds[4][160];                 // [wave][row*10 + h]
  __shared__ unsigned short feat_lds[4][16 * 72]; // [wave][row*72 + col]

  bf16x8 bfE[4][2], bfO[4][2];
  float beV[4], boV[4];
#pragma unroll
  for (int nb = 0; nb < 4; ++nb) {
    beV[nb] = be[nb * 16 + n15];
    boV[nb] = boe[nb * 16 + n15];
#pragma unroll
    for (int kb = 0; kb < 2; ++kb)
#pragma unroll
      for (int j = 0; j < 8; ++j) {
        bfE[nb][kb][j] = (short)f2bf(We[(kb * 32 + g * 8 + j) * 64 + nb * 16 + n15]);
        bfO[nb][kb][j] = (short)f2bf(Woe[(kb * 32 + g * 8 + j) * 64 + nb * 16 + n15]);
      }
  }

  const int ntiles = (E + 15) >> 4;
  const int nit = (ntiles + 3) >> 2;
  for (int it = blockIdx.x; it < nit; it += gridDim.x) {
    const int m0 = ((it << 2) + wv) << 4;
    const int arow = m0 + n15;
    // A: he row (fp32 -> bf16)
    bf16x8 a0, a1;
    if (arow < E) {
      const float* ap = he + (size_t)arow * 64 + g * 8;
      f32x4 x0 = *(const f32x4*)ap, x1 = *(const f32x4*)(ap + 4);
      f32x4 x2 = *(const f32x4*)(ap + 32), x3 = *(const f32x4*)(ap + 36);
#pragma unroll
      for (int j = 0; j < 4; ++j) {
        a0[j] = (short)f2bf(x0[j]); a0[4 + j] = (short)f2bf(x1[j]);
        a1[j] = (short)f2bf(x2[j]); a1[4 + j] = (short)f2bf(x3[j]);
      }
    } else {
#pragma unroll
      for (int j = 0; j < 8; ++j) { a0[j] = 0; a1[j] = 0; }
    }
    // elin (bias-seeded accumulators)
    f32x4 acc[4];
#pragma unroll
    for (int nb = 0; nb < 4; ++nb) {
      acc[nb] = (f32x4){beV[nb], beV[nb], beV[nb], beV[nb]};
      acc[nb] = __builtin_amdgcn_mfma_f32_16x16x32_bf16(a0, bfE[nb][0], acc[nb], 0, 0, 0);
      acc[nb] = __builtin_amdgcn_mfma_f32_16x16x32_bf16(a1, bfE[nb][1], acc[nb], 0, 0, 0);
    }
    // PER-HEAD gate: row=g*4+r, head=n15&7. cols with col%8==h are nb*16+{h,h+8}:
    // sum the 4 nb-quadrants then pair n15 <-> n15+8. Fold 1/sqrt(8).
    float gc[4];
#pragma unroll
    for (int r = 0; r < 4; ++r) {
      float s = acc[0][r] + acc[1][r] + acc[2][r] + acc[3][r];
      s += __shfl_xor(s, 8, 64);
      gc[r] = s * 0.35355339059327373f;
    }
    // tiled q.k: lane covers cols g*16..g*16+15 of edge m0+n15
    const int esafe = (arow < E) ? arow : (E - 1);
    const int rq = rowi[esafe], rc = coli[esafe];
    const unsigned short* qp = qb + (size_t)rq * 64 + g * 16;
    const unsigned short* kp = kbuf + (size_t)rc * 64 + g * 16;
    bf16x8 qv0 = *(const bf16x8*)qp, qv1 = *(const bf16x8*)(qp + 8);
    bf16x8 kv0 = *(const bf16x8*)kp, kv1 = *(const bf16x8*)(kp + 8);
    float p[8];
#pragma unroll
    for (int j = 0; j < 8; ++j)
      p[j] = bf2f((unsigned short)qv0[j]) * bf2f((unsigned short)kv0[j])
           + bf2f((unsigned short)qv1[j]) * bf2f((unsigned short)kv1[j]);
#pragma unroll
    for (int j = 0; j < 8; ++j) {
      p[j] += __shfl_xor(p[j], 16, 64);
      p[j] += __shfl_xor(p[j], 32, 64);
    }
    // p -> LDS (edge-row layout), re-read in C-row layout
    if (l < 16) {
      float2* sp = (float2*)&s_lds[wv][n15 * 10];
#pragma unroll
      for (int j = 0; j < 4; ++j) sp[j] = make_float2(p[2 * j], p[2 * j + 1]);
    }
    __syncthreads();
    float srow[4];
#pragma unroll
    for (int r = 0; r < 4; ++r)
      srow[r] = s_lds[wv][(g * 4 + r) * 10 + h] * gc[r];
    // gated scores out
#pragma unroll
    for (int r = 0; r < 4; ++r) {
      int orow = m0 + g * 4 + r;
      if (n15 < 8 && orow < E) scores[(size_t)orow * 8 + n15] = srow[r];
    }
    // feat = s*elin -> LDS transpose tile
#pragma unroll
    for (int nb = 0; nb < 4; ++nb)
#pragma unroll
      for (int r = 0; r < 4; ++r)
        feat_lds[wv][(g * 4 + r) * 72 + nb * 16 + n15] = f2bf(srow[r] * acc[nb][r]);
    __syncthreads();
    const unsigned short* fpt = &feat_lds[wv][n15 * 72 + g * 8];
    a0 = *(const bf16x8*)fpt;
    a1 = *(const bf16x8*)(fpt + 32);
#pragma unroll
    for (int nb = 0; nb < 4; ++nb) {
      f32x4 a2 = (f32x4){boV[nb], boV[nb], boV[nb], boV[nb]};
      a2 = __builtin_amdgcn_mfma_f32_16x16x32_bf16(a0, bfO[nb][0], a2, 0, 0, 0);
      a2 = __builtin_amdgcn_mfma_f32_16x16x32_bf16(a1, bfO[nb][1], a2, 0, 0, 0);
#pragma unroll
      for (int r = 0; r < 4; ++r) {
        int orow = m0 + g * 4 + r;
        if (orow < E) oe[(size_t)orow * 64 + nb * 16 + n15] = a2[r];
      }
    }
  }
}

// ---------------- CSR build ----------------
__global__ void hist_kernel(const int* __restrict__ row, int* __restrict__ deg, int E) {
  int gid = blockIdx.x * blockDim.x + threadIdx.x;
  if (gid < E) atomicAdd(&deg[row[gid]], 1);
}

#define SCAN_B 256
#define SCAN_E 8
__global__ void scan1_kernel(const int* __restrict__ deg, int* __restrict__ rowptr,
                             int* __restrict__ blksum, int n) {
  __shared__ int sh[SCAN_B];
  int base = blockIdx.x * (SCAN_B * SCAN_E) + threadIdx.x * SCAN_E;
  int v[SCAN_E];
  int s = 0;
#pragma unroll
  for (int j = 0; j < SCAN_E; ++j) {
    v[j] = (base + j < n) ? deg[base + j] : 0;
    s += v[j];
  }
  sh[threadIdx.x] = s;
  __syncthreads();
  for (int off = 1; off < SCAN_B; off <<= 1) {
    int t = (threadIdx.x >= off) ? sh[threadIdx.x - off] : 0;
    __syncthreads();
    sh[threadIdx.x] += t;
    __syncthreads();
  }
  if (threadIdx.x == SCAN_B - 1) blksum[blockIdx.x] = sh[SCAN_B - 1];
  int run = sh[threadIdx.x] - s;
#pragma unroll
  for (int j = 0; j < SCAN_E; ++j) {
    if (base + j < n) rowptr[base + j] = run;
    run += v[j];
  }
}

__global__ void scan2_kernel(int* __restrict__ blksum, int nb) {
  __shared__ int sh[SCAN_B];
  int v = (threadIdx.x < nb) ? blksum[threadIdx.x] : 0;
  sh[threadIdx.x] = v;
  __syncthreads();
  for (int off = 1; off < SCAN_B; off <<= 1) {
    int t = (threadIdx.x >= off) ? sh[threadIdx.x - off] : 0;
    __syncthreads();
    sh[threadIdx.x] += t;
    __syncthreads();
  }
  if (threadIdx.x < nb) blksum[threadIdx.x] = sh[threadIdx.x] - v;
}

__global__ void scan3_kernel(int* __restrict__ rowptr, int* __restrict__ cursor,
                             const int* __restrict__ blksum, int n) {
  int i = blockIdx.x * blockDim.x + threadIdx.x;
  if (i >= n) return;
  int v = rowptr[i] + blksum[i / (SCAN_B * SCAN_E)];
  rowptr[i] = v;
  cursor[i] = v;
}

__global__ void scatter_kernel(const int* __restrict__ row, const int* __restrict__ col,
                               int* __restrict__ cursor, int* __restrict__ eidx,
                               int* __restrict__ ecol, int E) {
  int gid = blockIdx.x * blockDim.x + threadIdx.x;
  if (gid >= E) return;
  int r = row[gid];
  int slot = atomicAdd(&cursor[r], 1);
  eidx[slot] = gid;
  ecol[slot] = col[gid];
}

// One wave per row: online softmax + weighted-V accumulation, single write.
__global__ void __launch_bounds__(256) row_attn_kernel(const float* __restrict__ scores,
    const int* __restrict__ rowptr, const int* __restrict__ deg,
    const int* __restrict__ eidx, const int* __restrict__ ecol,
    const unsigned short* __restrict__ vb, float* __restrict__ hout, int n) {
  int gid = blockIdx.x * blockDim.x + threadIdx.x;
  int r = gid >> 6, lane = threadIdx.x & 63;
  if (r >= n) return;
  int start = rowptr[r], dg = deg[r];
  int h = lane & 7;
  float m = -3.4e38f, den = 0.f, acc = 0.f;
  for (int i = 0; i < dg; ++i) {
    int eid = eidx[start + i];
    int c = ecol[start + i];
    float s = scores[(size_t)eid * 8 + h];
    float vv = bf2f(vb[(size_t)c * 64 + lane]);
    float mn = fmaxf(m, s);
    float corr = __expf(m - mn);
    float ex = __expf(s - mn);
    den = den * corr + ex;
    acc = acc * corr + ex * vv;
    m = mn;
  }
  hout[(size_t)r * 64 + lane] = (dg > 0) ? acc / den : 0.f;
}

extern "C" void kernel_launch(void* const* d_in, const int* in_sizes, int n_in,
                              void* d_out, int out_size, void* d_ws, size_t ws_size,
                              hipStream_t stream) {
  const float* hx  = (const float*)d_in[0];
  const float* he  = (const float*)d_in[1];
  const int*   row = (const int*)d_in[2];
  const int*   col = (const int*)d_in[3];
  const float* Wq = (const float*)d_in[4],  *bq = (const float*)d_in[5];
  const float* Wk = (const float*)d_in[6],  *bk = (const float*)d_in[7];
  const float* Wv = (const float*)d_in[8],  *bv = (const float*)d_in[9];
  const float* We = (const float*)d_in[10], *be = (const float*)d_in[11];
  const float* Woh = (const float*)d_in[12], *boh = (const float*)d_in[13];
  const float* Woe = (const float*)d_in[14], *boe = (const float*)d_in[15];

  const int n = in_sizes[0] / 64;
  const int E = in_sizes[2];

  float* out = (float*)d_out;
  float* oh = out;                   // n*64 fp32
  float* oe = out + (size_t)n * 64;  // E*64 fp32

  // ws: qb,kb,vbuf (n*64 bf16) | scores (E*8 f32) | hout (n*64 f32)
  // CSR arrays overlay qb/kb after edge_fused completes.
  unsigned short* qb   = (unsigned short*)d_ws;
  unsigned short* kb   = qb + (size_t)n * 64;
  unsigned short* vbuf = kb + (size_t)n * 64;
  float* scores = (float*)(vbuf + (size_t)n * 64);
  float* hout   = scores + (size_t)E * 8;

  int* deg    = (int*)qb;
  int* rowptr = deg + n;
  int* cursor = rowptr + n;
  int* blksum = cursor + n;
  int* eidx   = blksum + 256;
  int* ecol   = eidx + (size_t)E;

  const int nb_scan = (n + SCAN_B * SCAN_E - 1) / (SCAN_B * SCAN_E);

  qkv3_kernel<<<512, 256, 0, stream>>>(hx, Wq, bq, Wk, bk, Wv, bv, qb, kb, vbuf, n);
  edge_fused_kernel<<<2048, 256, 0, stream>>>(he, row, col, qb, kb, We, be, Woe, boe,
                                              oe, scores, E);

  // CSR build (overlays dead qb/kb region)
  hipMemsetAsync(deg, 0, (size_t)n * 4, stream);
  hist_kernel<<<(E + 255) / 256, 256, 0, stream>>>(row, deg, E);
  scan1_kernel<<<nb_scan, SCAN_B, 0, stream>>>(deg, rowptr, blksum, n);
  scan2_kernel<<<1, SCAN_B, 0, stream>>>(blksum, nb_scan);
  scan3_kernel<<<(n + 255) / 256, 256, 0, stream>>>(rowptr, cursor, blksum, n);
  scatter_kernel<<<(E + 255) / 256, 256, 0, stream>>>(row, col, cursor, eidx, ecol, E);

  row_attn_kernel<<<(n + 3) / 4, 256, 0, stream>>>(scores, rowptr, deg, eidx, ecol,
                                                   vbuf, hout, n);
  gemm64_kernel<false, false><<<512, 256, 0, stream>>>(hout, Woh, boh, oh, n);
}

// Round 6
// 598.513 us; speedup vs baseline: 5.2030x; 1.0704x over previous
//
#include <hip/hip_runtime.h>

typedef __attribute__((ext_vector_type(8))) short bf16x8;
typedef __attribute__((ext_vector_type(4))) float f32x4;

__device__ __forceinline__ unsigned short f2bf(float f) {
  unsigned u = __float_as_uint(f);
  return (unsigned short)((u + 0x7fffu + ((u >> 16) & 1u)) >> 16);  // RTN
}
__device__ __forceinline__ float bf2f(unsigned short h) {
  return __uint_as_float(((unsigned)h) << 16);
}

// ---------------- GEMM64: out[M,64] = A[M,64] @ W[64,64] + b ----------------
template<bool IN_BF16, bool OUT_BF16>
__global__ void __launch_bounds__(256) gemm64_kernel(const void* __restrict__ Ain,
    const float* __restrict__ W, const float* __restrict__ bias,
    void* __restrict__ Out, int M) {
  const int tid = threadIdx.x;
  const int l = tid & 63;
  const int g = l >> 4;
  const int n15 = l & 15;

  bf16x8 bfrag[4][2];
  float bv[4];
#pragma unroll
  for (int nb = 0; nb < 4; ++nb) {
    bv[nb] = bias[nb * 16 + n15];
#pragma unroll
    for (int kb = 0; kb < 2; ++kb)
#pragma unroll
      for (int j = 0; j < 8; ++j)
        bfrag[nb][kb][j] = (short)f2bf(W[(kb * 32 + g * 8 + j) * 64 + nb * 16 + n15]);
  }

  int wid = (blockIdx.x * blockDim.x + tid) >> 6;
  int nw = (gridDim.x * blockDim.x) >> 6;
  int ntiles = (M + 15) >> 4;
  for (int t = wid; t < ntiles; t += nw) {
    int m0 = t << 4;
    int arow = m0 + n15;
    bf16x8 a0, a1;
    if (arow < M) {
      if constexpr (IN_BF16) {
        const unsigned short* ap = (const unsigned short*)Ain + (size_t)arow * 64 + g * 8;
        a0 = *(const bf16x8*)ap;
        a1 = *(const bf16x8*)(ap + 32);
      } else {
        const float* ap = (const float*)Ain + (size_t)arow * 64 + g * 8;
        f32x4 x0 = *(const f32x4*)ap, x1 = *(const f32x4*)(ap + 4);
        f32x4 x2 = *(const f32x4*)(ap + 32), x3 = *(const f32x4*)(ap + 36);
#pragma unroll
        for (int j = 0; j < 4; ++j) {
          a0[j] = (short)f2bf(x0[j]); a0[4 + j] = (short)f2bf(x1[j]);
          a1[j] = (short)f2bf(x2[j]); a1[4 + j] = (short)f2bf(x3[j]);
        }
      }
    } else {
#pragma unroll
      for (int j = 0; j < 8; ++j) { a0[j] = 0; a1[j] = 0; }
    }
    f32x4 acc[4];
#pragma unroll
    for (int nb = 0; nb < 4; ++nb) {
      acc[nb] = (f32x4){bv[nb], bv[nb], bv[nb], bv[nb]};
      acc[nb] = __builtin_amdgcn_mfma_f32_16x16x32_bf16(a0, bfrag[nb][0], acc[nb], 0, 0, 0);
      acc[nb] = __builtin_amdgcn_mfma_f32_16x16x32_bf16(a1, bfrag[nb][1], acc[nb], 0, 0, 0);
    }
#pragma unroll
    for (int nb = 0; nb < 4; ++nb)
#pragma unroll
      for (int r = 0; r < 4; ++r) {
        int orow = m0 + g * 4 + r;
        if (orow < M) {
          float val = acc[nb][r];
          size_t oidx = (size_t)orow * 64 + nb * 16 + n15;
          if constexpr (OUT_BF16) ((unsigned short*)Out)[oidx] = f2bf(val);
          else                    ((float*)Out)[oidx] = val;
        }
      }
  }
}

// Fused q/k/v: 3 weight sets resident, hx read once, bf16 outputs.
__global__ void __launch_bounds__(256) qkv3_kernel(const float* __restrict__ hx,
    const float* __restrict__ Wq, const float* __restrict__ bq,
    const float* __restrict__ Wk, const float* __restrict__ bk,
    const float* __restrict__ Wv, const float* __restrict__ bv,
    unsigned short* __restrict__ q, unsigned short* __restrict__ k,
    unsigned short* __restrict__ v, int M) {
  const int tid = threadIdx.x;
  const int l = tid & 63;
  const int g = l >> 4;
  const int n15 = l & 15;
  const float* Ws[3] = {Wq, Wk, Wv};
  const float* bs[3] = {bq, bk, bv};
  unsigned short* outs[3] = {q, k, v};

  bf16x8 bfrag[3][4][2];
  float bvv[3][4];
#pragma unroll
  for (int w = 0; w < 3; ++w)
#pragma unroll
    for (int nb = 0; nb < 4; ++nb) {
      bvv[w][nb] = bs[w][nb * 16 + n15];
#pragma unroll
      for (int kb = 0; kb < 2; ++kb)
#pragma unroll
        for (int j = 0; j < 8; ++j)
          bfrag[w][nb][kb][j] = (short)f2bf(Ws[w][(kb * 32 + g * 8 + j) * 64 + nb * 16 + n15]);
    }

  int wid = (blockIdx.x * blockDim.x + tid) >> 6;
  int nw = (gridDim.x * blockDim.x) >> 6;
  int ntiles = (M + 15) >> 4;
  for (int t = wid; t < ntiles; t += nw) {
    int m0 = t << 4;
    int arow = m0 + n15;
    bf16x8 a0, a1;
    if (arow < M) {
      const float* ap = hx + (size_t)arow * 64 + g * 8;
      f32x4 x0 = *(const f32x4*)ap, x1 = *(const f32x4*)(ap + 4);
      f32x4 x2 = *(const f32x4*)(ap + 32), x3 = *(const f32x4*)(ap + 36);
#pragma unroll
      for (int j = 0; j < 4; ++j) {
        a0[j] = (short)f2bf(x0[j]); a0[4 + j] = (short)f2bf(x1[j]);
        a1[j] = (short)f2bf(x2[j]); a1[4 + j] = (short)f2bf(x3[j]);
      }
    } else {
#pragma unroll
      for (int j = 0; j < 8; ++j) { a0[j] = 0; a1[j] = 0; }
    }
#pragma unroll
    for (int w = 0; w < 3; ++w) {
      f32x4 acc[4];
#pragma unroll
      for (int nb = 0; nb < 4; ++nb) {
        acc[nb] = (f32x4){bvv[w][nb], bvv[w][nb], bvv[w][nb], bvv[w][nb]};
        acc[nb] = __builtin_amdgcn_mfma_f32_16x16x32_bf16(a0, bfrag[w][nb][0], acc[nb], 0, 0, 0);
        acc[nb] = __builtin_amdgcn_mfma_f32_16x16x32_bf16(a1, bfrag[w][nb][1], acc[nb], 0, 0, 0);
      }
#pragma unroll
      for (int nb = 0; nb < 4; ++nb)
#pragma unroll
        for (int r = 0; r < 4; ++r) {
          int orow = m0 + g * 4 + r;
          if (orow < M)
            outs[w][(size_t)orow * 64 + nb * 16 + n15] = f2bf(acc[nb][r]);
        }
    }
  }
}

// ---------------- Fused edge pipeline (now also builds the degree histogram) --------
// Per 16-edge tile (one wave):
//   elin = he@We+be (MFMA, fp32 acc)             [C: row=g*4+r, col=nb*16+n15]
//   gate[row,h] = sum_dh elin[row, dh*8+h]  ==  sum_nb acc + shfl_xor(,8)  (per-head)
//   p[e,h] = q[row[e]].k[col[e]] per head (tiled, lane=edge n15 x colblock g)
//   s = p/sqrt(8)*gate -> scores[e,h] ; deg[row[e]]++ (g==0 lanes)
//   feat = s*elin -> LDS transpose -> A-frag ; oe = feat@Woe+boe
__global__ void __launch_bounds__(256, 3) edge_fused_kernel(
    const float* __restrict__ he,
    const int* __restrict__ rowi, const int* __restrict__ coli,
    const unsigned short* __restrict__ qb, const unsigned short* __restrict__ kbuf,
    const float* __restrict__ We, const float* __restrict__ be,
    const float* __restrict__ Woe, const float* __restrict__ boe,
    float* __restrict__ oe, float* __restrict__ scores,
    int* __restrict__ deg, int E) {
  const int tid = threadIdx.x;
  const int wv = tid >> 6;
  const int l = tid & 63;
  const int g = l >> 4;
  const int n15 = l & 15;
  const int h = n15 & 7;

  __shared__ float s_lds[4][160];                 // [wave][row*10 + h]
  __shared__ unsigned short feat_lds[4][16 * 72]; // [wave][row*72 + col]

  bf16x8 bfE[4][2], bfO[4][2];
  float beV[4], boV[4];
#pragma unroll
  for (int nb = 0; nb < 4; ++nb) {
    beV[nb] = be[nb * 16 + n15];
    boV[nb] = boe[nb * 16 + n15];
#pragma unroll
    for (int kb = 0; kb < 2; ++kb)
#pragma unroll
      for (int j = 0; j < 8; ++j) {
        bfE[nb][kb][j] = (short)f2bf(We[(kb * 32 + g * 8 + j) * 64 + nb * 16 + n15]);
        bfO[nb][kb][j] = (short)f2bf(Woe[(kb * 32 + g * 8 + j) * 64 + nb * 16 + n15]);
      }
  }

  const int ntiles = (E + 15) >> 4;
  const int nit = (ntiles + 3) >> 2;
  for (int it = blockIdx.x; it < nit; it += gridDim.x) {
    const int m0 = ((it << 2) + wv) << 4;
    const int arow = m0 + n15;
    // A: he row (fp32 -> bf16)
    bf16x8 a0, a1;
    if (arow < E) {
      const float* ap = he + (size_t)arow * 64 + g * 8;
      f32x4 x0 = *(const f32x4*)ap, x1 = *(const f32x4*)(ap + 4);
      f32x4 x2 = *(const f32x4*)(ap + 32), x3 = *(const f32x4*)(ap + 36);
#pragma unroll
      for (int j = 0; j < 4; ++j) {
        a0[j] = (short)f2bf(x0[j]); a0[4 + j] = (short)f2bf(x1[j]);
        a1[j] = (short)f2bf(x2[j]); a1[4 + j] = (short)f2bf(x3[j]);
      }
    } else {
#pragma unroll
      for (int j = 0; j < 8; ++j) { a0[j] = 0; a1[j] = 0; }
    }
    // elin (bias-seeded accumulators)
    f32x4 acc[4];
#pragma unroll
    for (int nb = 0; nb < 4; ++nb) {
      acc[nb] = (f32x4){beV[nb], beV[nb], beV[nb], beV[nb]};
      acc[nb] = __builtin_amdgcn_mfma_f32_16x16x32_bf16(a0, bfE[nb][0], acc[nb], 0, 0, 0);
      acc[nb] = __builtin_amdgcn_mfma_f32_16x16x32_bf16(a1, bfE[nb][1], acc[nb], 0, 0, 0);
    }
    // per-head gate: sum the 4 nb-quadrants then pair n15 <-> n15+8; fold 1/sqrt(8)
    float gc[4];
#pragma unroll
    for (int r = 0; r < 4; ++r) {
      float s = acc[0][r] + acc[1][r] + acc[2][r] + acc[3][r];
      s += __shfl_xor(s, 8, 64);
      gc[r] = s * 0.35355339059327373f;
    }
    // tiled q.k: lane covers cols g*16..g*16+15 of edge m0+n15
    const int esafe = (arow < E) ? arow : (E - 1);
    const int rq = rowi[esafe], rc = coli[esafe];
    // degree histogram: one lane group per edge
    if (g == 0 && arow < E) atomicAdd(&deg[rq], 1);
    const unsigned short* qp = qb + (size_t)rq * 64 + g * 16;
    const unsigned short* kp = kbuf + (size_t)rc * 64 + g * 16;
    bf16x8 qv0 = *(const bf16x8*)qp, qv1 = *(const bf16x8*)(qp + 8);
    bf16x8 kv0 = *(const bf16x8*)kp, kv1 = *(const bf16x8*)(kp + 8);
    float p[8];
#pragma unroll
    for (int j = 0; j < 8; ++j)
      p[j] = bf2f((unsigned short)qv0[j]) * bf2f((unsigned short)kv0[j])
           + bf2f((unsigned short)qv1[j]) * bf2f((unsigned short)kv1[j]);
#pragma unroll
    for (int j = 0; j < 8; ++j) {
      p[j] += __shfl_xor(p[j], 16, 64);
      p[j] += __shfl_xor(p[j], 32, 64);
    }
    // p -> LDS (edge-row layout), re-read in C-row layout
    if (l < 16) {
      float2* sp = (float2*)&s_lds[wv][n15 * 10];
#pragma unroll
      for (int j = 0; j < 4; ++j) sp[j] = make_float2(p[2 * j], p[2 * j + 1]);
    }
    __syncthreads();
    float srow[4];
#pragma unroll
    for (int r = 0; r < 4; ++r)
      srow[r] = s_lds[wv][(g * 4 + r) * 10 + h] * gc[r];
    // gated scores out
#pragma unroll
    for (int r = 0; r < 4; ++r) {
      int orow = m0 + g * 4 + r;
      if (n15 < 8 && orow < E) scores[(size_t)orow * 8 + n15] = srow[r];
    }
    // feat = s*elin -> LDS transpose tile
#pragma unroll
    for (int nb = 0; nb < 4; ++nb)
#pragma unroll
      for (int r = 0; r < 4; ++r)
        feat_lds[wv][(g * 4 + r) * 72 + nb * 16 + n15] = f2bf(srow[r] * acc[nb][r]);
    __syncthreads();
    const unsigned short* fpt = &feat_lds[wv][n15 * 72 + g * 8];
    a0 = *(const bf16x8*)fpt;
    a1 = *(const bf16x8*)(fpt + 32);
#pragma unroll
    for (int nb = 0; nb < 4; ++nb) {
      f32x4 a2 = (f32x4){boV[nb], boV[nb], boV[nb], boV[nb]};
      a2 = __builtin_amdgcn_mfma_f32_16x16x32_bf16(a0, bfO[nb][0], a2, 0, 0, 0);
      a2 = __builtin_amdgcn_mfma_f32_16x16x32_bf16(a1, bfO[nb][1], a2, 0, 0, 0);
#pragma unroll
      for (int r = 0; r < 4; ++r) {
        int orow = m0 + g * 4 + r;
        if (orow < E) oe[(size_t)orow * 64 + nb * 16 + n15] = a2[r];
      }
    }
  }
}

// ---------------- CSR build ----------------
__global__ void zero_kernel(int* __restrict__ p, int n) {
  int i = blockIdx.x * blockDim.x + threadIdx.x;
  if (i < n) p[i] = 0;
}

#define SCAN_B 256
#define SCAN_E 8
__global__ void scan1_kernel(const int* __restrict__ deg, int* __restrict__ rowptr,
                             int* __restrict__ blksum, int n) {
  __shared__ int sh[SCAN_B];
  int base = blockIdx.x * (SCAN_B * SCAN_E) + threadIdx.x * SCAN_E;
  int v[SCAN_E];
  int s = 0;
#pragma unroll
  for (int j = 0; j < SCAN_E; ++j) {
    v[j] = (base + j < n) ? deg[base + j] : 0;
    s += v[j];
  }
  sh[threadIdx.x] = s;
  __syncthreads();
  for (int off = 1; off < SCAN_B; off <<= 1) {
    int t = (threadIdx.x >= off) ? sh[threadIdx.x - off] : 0;
    __syncthreads();
    sh[threadIdx.x] += t;
    __syncthreads();
  }
  if (threadIdx.x == SCAN_B - 1) blksum[blockIdx.x] = sh[SCAN_B - 1];
  int run = sh[threadIdx.x] - s;
#pragma unroll
  for (int j = 0; j < SCAN_E; ++j) {
    if (base + j < n) rowptr[base + j] = run;
    run += v[j];
  }
}

__global__ void scan2_kernel(int* __restrict__ blksum, int nb) {
  __shared__ int sh[SCAN_B];
  int v = (threadIdx.x < nb) ? blksum[threadIdx.x] : 0;
  sh[threadIdx.x] = v;
  __syncthreads();
  for (int off = 1; off < SCAN_B; off <<= 1) {
    int t = (threadIdx.x >= off) ? sh[threadIdx.x - off] : 0;
    __syncthreads();
    sh[threadIdx.x] += t;
    __syncthreads();
  }
  if (threadIdx.x < nb) blksum[threadIdx.x] = sh[threadIdx.x] - v;
}

__global__ void scan3_kernel(int* __restrict__ rowptr, int* __restrict__ cursor,
                             const int* __restrict__ blksum, int n) {
  int i = blockIdx.x * blockDim.x + threadIdx.x;
  if (i >= n) return;
  int v = rowptr[i] + blksum[i / (SCAN_B * SCAN_E)];
  rowptr[i] = v;
  cursor[i] = v;
}

__global__ void scatter_kernel(const int* __restrict__ row, const int* __restrict__ col,
                               int* __restrict__ cursor, int* __restrict__ eidx,
                               int* __restrict__ ecol, int E) {
  int gid = blockIdx.x * blockDim.x + threadIdx.x;
  if (gid >= E) return;
  int r = row[gid];
  int slot = atomicAdd(&cursor[r], 1);
  eidx[slot] = gid;
  ecol[slot] = col[gid];
}

// One wave per row: online softmax + weighted-V accumulation, single write.
__global__ void __launch_bounds__(256) row_attn_kernel(const float* __restrict__ scores,
    const int* __restrict__ rowptr, const int* __restrict__ deg,
    const int* __restrict__ eidx, const int* __restrict__ ecol,
    const unsigned short* __restrict__ vb, float* __restrict__ hout, int n) {
  int gid = blockIdx.x * blockDim.x + threadIdx.x;
  int r = gid >> 6, lane = threadIdx.x & 63;
  if (r >= n) return;
  int start = rowptr[r], dg = deg[r];
  int h = lane & 7;
  float m = -3.4e38f, den = 0.f, acc = 0.f;
  for (int i = 0; i < dg; ++i) {
    int eid = eidx[start + i];
    int c = ecol[start + i];
    float s = scores[(size_t)eid * 8 + h];
    float vv = bf2f(vb[(size_t)c * 64 + lane]);
    float mn = fmaxf(m, s);
    float corr = __expf(m - mn);
    float ex = __expf(s - mn);
    den = den * corr + ex;
    acc = acc * corr + ex * vv;
    m = mn;
  }
  hout[(size_t)r * 64 + lane] = (dg > 0) ? acc / den : 0.f;
}

extern "C" void kernel_launch(void* const* d_in, const int* in_sizes, int n_in,
                              void* d_out, int out_size, void* d_ws, size_t ws_size,
                              hipStream_t stream) {
  const float* hx  = (const float*)d_in[0];
  const float* he  = (const float*)d_in[1];
  const int*   row = (const int*)d_in[2];
  const int*   col = (const int*)d_in[3];
  const float* Wq = (const float*)d_in[4],  *bq = (const float*)d_in[5];
  const float* Wk = (const float*)d_in[6],  *bk = (const float*)d_in[7];
  const float* Wv = (const float*)d_in[8],  *bv = (const float*)d_in[9];
  const float* We = (const float*)d_in[10], *be = (const float*)d_in[11];
  const float* Woh = (const float*)d_in[12], *boh = (const float*)d_in[13];
  const float* Woe = (const float*)d_in[14], *boe = (const float*)d_in[15];

  const int n = in_sizes[0] / 64;
  const int E = in_sizes[2];

  float* out = (float*)d_out;
  float* oh = out;                   // n*64 fp32
  float* oe = out + (size_t)n * 64;  // E*64 fp32

  // ws (no overlays): qb,kb,vbuf (n*64 bf16) | scores (E*8 f32) | hout (n*64 f32)
  //                 | deg,rowptr,cursor (n int) | blksum (256) | eidx,ecol (E int)
  // total ~130 MB (round-2 layout of ~326 MB fit, so this is safe).
  unsigned short* qb   = (unsigned short*)d_ws;
  unsigned short* kb   = qb + (size_t)n * 64;
  unsigned short* vbuf = kb + (size_t)n * 64;
  float* scores = (float*)(vbuf + (size_t)n * 64);
  float* hout   = scores + (size_t)E * 8;

  int* deg    = (int*)(hout + (size_t)n * 64);
  int* rowptr = deg + n;
  int* cursor = rowptr + n;
  int* blksum = cursor + n;
  int* eidx   = blksum + 256;
  int* ecol   = eidx + (size_t)E;

  const int nb_scan = (n + SCAN_B * SCAN_E - 1) / (SCAN_B * SCAN_E);

  zero_kernel<<<(n + 255) / 256, 256, 0, stream>>>(deg, n);
  qkv3_kernel<<<512, 256, 0, stream>>>(hx, Wq, bq, Wk, bk, Wv, bv, qb, kb, vbuf, n);
  edge_fused_kernel<<<2048, 256, 0, stream>>>(he, row, col, qb, kb, We, be, Woe, boe,
                                              oe, scores, deg, E);

  scan1_kernel<<<nb_scan, SCAN_B, 0, stream>>>(deg, rowptr, blksum, n);
  scan2_kernel<<<1, SCAN_B, 0, stream>>>(blksum, nb_scan);
  scan3_kernel<<<(n + 255) / 256, 256, 0, stream>>>(rowptr, cursor, blksum, n);
  scatter_kernel<<<(E + 255) / 256, 256, 0, stream>>>(row, col, cursor, eidx, ecol, E);

  row_attn_kernel<<<(n + 3) / 4, 256, 0, stream>>>(scores, rowptr, deg, eidx, ecol,
                                                   vbuf, hout, n);
  gemm64_kernel<false, false><<<512, 256, 0, stream>>>(hout, Woh, boh, oh, n);
}

// Round 7
// 567.983 us; speedup vs baseline: 5.4827x; 1.0538x over previous
//
#include <hip/hip_runtime.h>

typedef __attribute__((ext_vector_type(8))) short bf16x8;
typedef __attribute__((ext_vector_type(4))) float f32x4;

__device__ __forceinline__ unsigned short f2bf(float f) {
  unsigned u = __float_as_uint(f);
  return (unsigned short)((u + 0x7fffu + ((u >> 16) & 1u)) >> 16);  // RTN
}
__device__ __forceinline__ float bf2f(unsigned short h) {
  return __uint_as_float(((unsigned)h) << 16);
}

// Wave-local LDS fence: all of this wave's prior ds_writes complete before any
// following ds_read. (rule 18: sched_barrier after the waitcnt.)
__device__ __forceinline__ void lds_fence() {
  asm volatile("s_waitcnt lgkmcnt(0)" ::: "memory");
  __builtin_amdgcn_sched_barrier(0);
}

// ---------------- GEMM64: out[M,64] = A[M,64] @ W[64,64] + b ----------------
template<bool IN_BF16, bool OUT_BF16>
__global__ void __launch_bounds__(256) gemm64_kernel(const void* __restrict__ Ain,
    const float* __restrict__ W, const float* __restrict__ bias,
    void* __restrict__ Out, int M) {
  const int tid = threadIdx.x;
  const int l = tid & 63;
  const int g = l >> 4;
  const int n15 = l & 15;

  bf16x8 bfrag[4][2];
  float bv[4];
#pragma unroll
  for (int nb = 0; nb < 4; ++nb) {
    bv[nb] = bias[nb * 16 + n15];
#pragma unroll
    for (int kb = 0; kb < 2; ++kb)
#pragma unroll
      for (int j = 0; j < 8; ++j)
        bfrag[nb][kb][j] = (short)f2bf(W[(kb * 32 + g * 8 + j) * 64 + nb * 16 + n15]);
  }

  int wid = (blockIdx.x * blockDim.x + tid) >> 6;
  int nw = (gridDim.x * blockDim.x) >> 6;
  int ntiles = (M + 15) >> 4;
  for (int t = wid; t < ntiles; t += nw) {
    int m0 = t << 4;
    int arow = m0 + n15;
    bf16x8 a0, a1;
    if (arow < M) {
      if constexpr (IN_BF16) {
        const unsigned short* ap = (const unsigned short*)Ain + (size_t)arow * 64 + g * 8;
        a0 = *(const bf16x8*)ap;
        a1 = *(const bf16x8*)(ap + 32);
      } else {
        const float* ap = (const float*)Ain + (size_t)arow * 64 + g * 8;
        f32x4 x0 = *(const f32x4*)ap, x1 = *(const f32x4*)(ap + 4);
        f32x4 x2 = *(const f32x4*)(ap + 32), x3 = *(const f32x4*)(ap + 36);
#pragma unroll
        for (int j = 0; j < 4; ++j) {
          a0[j] = (short)f2bf(x0[j]); a0[4 + j] = (short)f2bf(x1[j]);
          a1[j] = (short)f2bf(x2[j]); a1[4 + j] = (short)f2bf(x3[j]);
        }
      }
    } else {
#pragma unroll
      for (int j = 0; j < 8; ++j) { a0[j] = 0; a1[j] = 0; }
    }
    f32x4 acc[4];
#pragma unroll
    for (int nb = 0; nb < 4; ++nb) {
      acc[nb] = (f32x4){bv[nb], bv[nb], bv[nb], bv[nb]};
      acc[nb] = __builtin_amdgcn_mfma_f32_16x16x32_bf16(a0, bfrag[nb][0], acc[nb], 0, 0, 0);
      acc[nb] = __builtin_amdgcn_mfma_f32_16x16x32_bf16(a1, bfrag[nb][1], acc[nb], 0, 0, 0);
    }
#pragma unroll
    for (int nb = 0; nb < 4; ++nb)
#pragma unroll
      for (int r = 0; r < 4; ++r) {
        int orow = m0 + g * 4 + r;
        if (orow < M) {
          float val = acc[nb][r];
          size_t oidx = (size_t)orow * 64 + nb * 16 + n15;
          if constexpr (OUT_BF16) ((unsigned short*)Out)[oidx] = f2bf(val);
          else                    ((float*)Out)[oidx] = val;
        }
      }
  }
}

// Fused q/k/v: 3 weight sets resident, hx read once, bf16 outputs.
__global__ void __launch_bounds__(256) qkv3_kernel(const float* __restrict__ hx,
    const float* __restrict__ Wq, const float* __restrict__ bq,
    const float* __restrict__ Wk, const float* __restrict__ bk,
    const float* __restrict__ Wv, const float* __restrict__ bv,
    unsigned short* __restrict__ q, unsigned short* __restrict__ k,
    unsigned short* __restrict__ v, int M) {
  const int tid = threadIdx.x;
  const int l = tid & 63;
  const int g = l >> 4;
  const int n15 = l & 15;
  const float* Ws[3] = {Wq, Wk, Wv};
  const float* bs[3] = {bq, bk, bv};
  unsigned short* outs[3] = {q, k, v};

  bf16x8 bfrag[3][4][2];
  float bvv[3][4];
#pragma unroll
  for (int w = 0; w < 3; ++w)
#pragma unroll
    for (int nb = 0; nb < 4; ++nb) {
      bvv[w][nb] = bs[w][nb * 16 + n15];
#pragma unroll
      for (int kb = 0; kb < 2; ++kb)
#pragma unroll
        for (int j = 0; j < 8; ++j)
          bfrag[w][nb][kb][j] = (short)f2bf(Ws[w][(kb * 32 + g * 8 + j) * 64 + nb * 16 + n15]);
    }

  int wid = (blockIdx.x * blockDim.x + tid) >> 6;
  int nw = (gridDim.x * blockDim.x) >> 6;
  int ntiles = (M + 15) >> 4;
  for (int t = wid; t < ntiles; t += nw) {
    int m0 = t << 4;
    int arow = m0 + n15;
    bf16x8 a0, a1;
    if (arow < M) {
      const float* ap = hx + (size_t)arow * 64 + g * 8;
      f32x4 x0 = *(const f32x4*)ap, x1 = *(const f32x4*)(ap + 4);
      f32x4 x2 = *(const f32x4*)(ap + 32), x3 = *(const f32x4*)(ap + 36);
#pragma unroll
      for (int j = 0; j < 4; ++j) {
        a0[j] = (short)f2bf(x0[j]); a0[4 + j] = (short)f2bf(x1[j]);
        a1[j] = (short)f2bf(x2[j]); a1[4 + j] = (short)f2bf(x3[j]);
      }
    } else {
#pragma unroll
      for (int j = 0; j < 8; ++j) { a0[j] = 0; a1[j] = 0; }
    }
#pragma unroll
    for (int w = 0; w < 3; ++w) {
      f32x4 acc[4];
#pragma unroll
      for (int nb = 0; nb < 4; ++nb) {
        acc[nb] = (f32x4){bvv[w][nb], bvv[w][nb], bvv[w][nb], bvv[w][nb]};
        acc[nb] = __builtin_amdgcn_mfma_f32_16x16x32_bf16(a0, bfrag[w][nb][0], acc[nb], 0, 0, 0);
        acc[nb] = __builtin_amdgcn_mfma_f32_16x16x32_bf16(a1, bfrag[w][nb][1], acc[nb], 0, 0, 0);
      }
#pragma unroll
      for (int nb = 0; nb < 4; ++nb)
#pragma unroll
        for (int r = 0; r < 4; ++r) {
          int orow = m0 + g * 4 + r;
          if (orow < M)
            outs[w][(size_t)orow * 64 + nb * 16 + n15] = f2bf(acc[nb][r]);
        }
    }
  }
}

// ---------------- Fused edge pipeline (barrier-free; scores written in CSR order) ----
__global__ void __launch_bounds__(256) edge_fused_kernel(
    const float* __restrict__ he,
    const int* __restrict__ rowi, const int* __restrict__ coli,
    const int* __restrict__ eslot,
    const unsigned short* __restrict__ qb, const unsigned short* __restrict__ kbuf,
    const float* __restrict__ We, const float* __restrict__ be,
    const float* __restrict__ Woe, const float* __restrict__ boe,
    float* __restrict__ oe, float* __restrict__ escores, int E) {
  const int tid = threadIdx.x;
  const int wv = tid >> 6;
  const int l = tid & 63;
  const int g = l >> 4;
  const int n15 = l & 15;
  const int h = n15 & 7;

  __shared__ float s_lds[4][160];                 // [wave][row*10 + h]
  __shared__ unsigned short feat_lds[4][16 * 72]; // [wave][row*72 + col]

  bf16x8 bfE[4][2], bfO[4][2];
  float beV[4], boV[4];
#pragma unroll
  for (int nb = 0; nb < 4; ++nb) {
    beV[nb] = be[nb * 16 + n15];
    boV[nb] = boe[nb * 16 + n15];
#pragma unroll
    for (int kb = 0; kb < 2; ++kb)
#pragma unroll
      for (int j = 0; j < 8; ++j) {
        bfE[nb][kb][j] = (short)f2bf(We[(kb * 32 + g * 8 + j) * 64 + nb * 16 + n15]);
        bfO[nb][kb][j] = (short)f2bf(Woe[(kb * 32 + g * 8 + j) * 64 + nb * 16 + n15]);
      }
  }

  const int ntiles = (E + 15) >> 4;
  const int nit = (ntiles + 3) >> 2;
  for (int it = blockIdx.x; it < nit; it += gridDim.x) {
    const int m0 = ((it << 2) + wv) << 4;
    const int arow = m0 + n15;
    // A: he row (fp32 -> bf16)
    bf16x8 a0, a1;
    if (arow < E) {
      const float* ap = he + (size_t)arow * 64 + g * 8;
      f32x4 x0 = *(const f32x4*)ap, x1 = *(const f32x4*)(ap + 4);
      f32x4 x2 = *(const f32x4*)(ap + 32), x3 = *(const f32x4*)(ap + 36);
#pragma unroll
      for (int j = 0; j < 4; ++j) {
        a0[j] = (short)f2bf(x0[j]); a0[4 + j] = (short)f2bf(x1[j]);
        a1[j] = (short)f2bf(x2[j]); a1[4 + j] = (short)f2bf(x3[j]);
      }
    } else {
#pragma unroll
      for (int j = 0; j < 8; ++j) { a0[j] = 0; a1[j] = 0; }
    }
    // elin (bias-seeded accumulators)
    f32x4 acc[4];
#pragma unroll
    for (int nb = 0; nb < 4; ++nb) {
      acc[nb] = (f32x4){beV[nb], beV[nb], beV[nb], beV[nb]};
      acc[nb] = __builtin_amdgcn_mfma_f32_16x16x32_bf16(a0, bfE[nb][0], acc[nb], 0, 0, 0);
      acc[nb] = __builtin_amdgcn_mfma_f32_16x16x32_bf16(a1, bfE[nb][1], acc[nb], 0, 0, 0);
    }
    // per-head gate: sum the 4 nb-quadrants then pair n15 <-> n15+8; fold 1/sqrt(8)
    float gc[4];
#pragma unroll
    for (int r = 0; r < 4; ++r) {
      float s = acc[0][r] + acc[1][r] + acc[2][r] + acc[3][r];
      s += __shfl_xor(s, 8, 64);
      gc[r] = s * 0.35355339059327373f;
    }
    // tiled q.k: lane covers cols g*16..g*16+15 of edge m0+n15
    const int esafe = (arow < E) ? arow : (E - 1);
    const int rq = rowi[esafe], rc = coli[esafe];
    const int slotv = eslot[esafe];  // lane with n15=x holds slot of edge m0+x
    const unsigned short* qp = qb + (size_t)rq * 64 + g * 16;
    const unsigned short* kp = kbuf + (size_t)rc * 64 + g * 16;
    bf16x8 qv0 = *(const bf16x8*)qp, qv1 = *(const bf16x8*)(qp + 8);
    bf16x8 kv0 = *(const bf16x8*)kp, kv1 = *(const bf16x8*)(kp + 8);
    float p[8];
#pragma unroll
    for (int j = 0; j < 8; ++j)
      p[j] = bf2f((unsigned short)qv0[j]) * bf2f((unsigned short)kv0[j])
           + bf2f((unsigned short)qv1[j]) * bf2f((unsigned short)kv1[j]);
#pragma unroll
    for (int j = 0; j < 8; ++j) {
      p[j] += __shfl_xor(p[j], 16, 64);
      p[j] += __shfl_xor(p[j], 32, 64);
    }
    // p -> LDS (edge-row layout), re-read in C-row layout (wave-local fence)
    if (l < 16) {
      float2* sp = (float2*)&s_lds[wv][n15 * 10];
#pragma unroll
      for (int j = 0; j < 4; ++j) sp[j] = make_float2(p[2 * j], p[2 * j + 1]);
    }
    lds_fence();
    float srow[4];
#pragma unroll
    for (int r = 0; r < 4; ++r)
      srow[r] = s_lds[wv][(g * 4 + r) * 10 + h] * gc[r];
    // gated scores out, directly into CSR slot order
#pragma unroll
    for (int r = 0; r < 4; ++r) {
      int orow = m0 + g * 4 + r;
      int slot = __shfl(slotv, g * 4 + r, 64);
      if (n15 < 8 && orow < E) escores[(size_t)slot * 8 + n15] = srow[r];
    }
    // feat = s*elin -> LDS transpose tile (wave-local fence)
#pragma unroll
    for (int nb = 0; nb < 4; ++nb)
#pragma unroll
      for (int r = 0; r < 4; ++r)
        feat_lds[wv][(g * 4 + r) * 72 + nb * 16 + n15] = f2bf(srow[r] * acc[nb][r]);
    lds_fence();
    const unsigned short* fpt = &feat_lds[wv][n15 * 72 + g * 8];
    a0 = *(const bf16x8*)fpt;
    a1 = *(const bf16x8*)(fpt + 32);
#pragma unroll
    for (int nb = 0; nb < 4; ++nb) {
      f32x4 a2 = (f32x4){boV[nb], boV[nb], boV[nb], boV[nb]};
      a2 = __builtin_amdgcn_mfma_f32_16x16x32_bf16(a0, bfO[nb][0], a2, 0, 0, 0);
      a2 = __builtin_amdgcn_mfma_f32_16x16x32_bf16(a1, bfO[nb][1], a2, 0, 0, 0);
#pragma unroll
      for (int r = 0; r < 4; ++r) {
        int orow = m0 + g * 4 + r;
        if (orow < E) oe[(size_t)orow * 64 + nb * 16 + n15] = a2[r];
      }
    }
  }
}

// ---------------- CSR build ----------------
__global__ void zero_kernel(int* __restrict__ p, int n) {
  int i = blockIdx.x * blockDim.x + threadIdx.x;
  if (i < n) p[i] = 0;
}

__global__ void hist_kernel(const int* __restrict__ row, int* __restrict__ deg, int E) {
  int gid = blockIdx.x * blockDim.x + threadIdx.x;
  if (gid < E) atomicAdd(&deg[row[gid]], 1);
}

#define SCAN_B 256
#define SCAN_E 8
__global__ void scan1_kernel(const int* __restrict__ deg, int* __restrict__ rowptr,
                             int* __restrict__ blksum, int n) {
  __shared__ int sh[SCAN_B];
  int base = blockIdx.x * (SCAN_B * SCAN_E) + threadIdx.x * SCAN_E;
  int v[SCAN_E];
  int s = 0;
#pragma unroll
  for (int j = 0; j < SCAN_E; ++j) {
    v[j] = (base + j < n) ? deg[base + j] : 0;
    s += v[j];
  }
  sh[threadIdx.x] = s;
  __syncthreads();
  for (int off = 1; off < SCAN_B; off <<= 1) {
    int t = (threadIdx.x >= off) ? sh[threadIdx.x - off] : 0;
    __syncthreads();
    sh[threadIdx.x] += t;
    __syncthreads();
  }
  if (threadIdx.x == SCAN_B - 1) blksum[blockIdx.x] = sh[SCAN_B - 1];
  int run = sh[threadIdx.x] - s;
#pragma unroll
  for (int j = 0; j < SCAN_E; ++j) {
    if (base + j < n) rowptr[base + j] = run;
    run += v[j];
  }
}

__global__ void scan2_kernel(int* __restrict__ blksum, int nb) {
  __shared__ int sh[SCAN_B];
  int v = (threadIdx.x < nb) ? blksum[threadIdx.x] : 0;
  sh[threadIdx.x] = v;
  __syncthreads();
  for (int off = 1; off < SCAN_B; off <<= 1) {
    int t = (threadIdx.x >= off) ? sh[threadIdx.x - off] : 0;
    __syncthreads();
    sh[threadIdx.x] += t;
    __syncthreads();
  }
  if (threadIdx.x < nb) blksum[threadIdx.x] = sh[threadIdx.x] - v;
}

__global__ void scan3_kernel(int* __restrict__ rowptr, int* __restrict__ cursor,
                             const int* __restrict__ blksum, int n) {
  int i = blockIdx.x * blockDim.x + threadIdx.x;
  if (i >= n) return;
  int v = rowptr[i] + blksum[i / (SCAN_B * SCAN_E)];
  rowptr[i] = v;
  cursor[i] = v;
}

// also records eslot[e] so scores can be written in CSR order by edge_fused
__global__ void scatter_kernel(const int* __restrict__ row, const int* __restrict__ col,
                               int* __restrict__ cursor, int* __restrict__ eslot,
                               int* __restrict__ ecol, int E) {
  int gid = blockIdx.x * blockDim.x + threadIdx.x;
  if (gid >= E) return;
  int r = row[gid];
  int slot = atomicAdd(&cursor[r], 1);
  eslot[gid] = slot;
  ecol[slot] = col[gid];
}

// One wave per row. Scores are pre-gated, small (|s|<~5): softmax without max-shift
// is mathematically identical; removes the dependent max chain -> full ILP.
__global__ void __launch_bounds__(256) row_attn_kernel(const float* __restrict__ escores,
    const int* __restrict__ rowptr, const int* __restrict__ deg,
    const int* __restrict__ ecol,
    const unsigned short* __restrict__ vb, float* __restrict__ hout, int n) {
  int gid = blockIdx.x * blockDim.x + threadIdx.x;
  int r = gid >> 6, lane = threadIdx.x & 63;
  if (r >= n) return;
  int start = rowptr[r], dg = deg[r];
  int h = lane & 7;
  float den = 0.f, acc = 0.f;
#pragma unroll 4
  for (int i = 0; i < dg; ++i) {
    int c = ecol[start + i];
    float ex = __expf(escores[(size_t)(start + i) * 8 + h]);
    float vv = bf2f(vb[(size_t)c * 64 + lane]);
    den += ex;
    acc += ex * vv;
  }
  hout[(size_t)r * 64 + lane] = (dg > 0) ? acc / den : 0.f;
}

extern "C" void kernel_launch(void* const* d_in, const int* in_sizes, int n_in,
                              void* d_out, int out_size, void* d_ws, size_t ws_size,
                              hipStream_t stream) {
  const float* hx  = (const float*)d_in[0];
  const float* he  = (const float*)d_in[1];
  const int*   row = (const int*)d_in[2];
  const int*   col = (const int*)d_in[3];
  const float* Wq = (const float*)d_in[4],  *bq = (const float*)d_in[5];
  const float* Wk = (const float*)d_in[6],  *bk = (const float*)d_in[7];
  const float* Wv = (const float*)d_in[8],  *bv = (const float*)d_in[9];
  const float* We = (const float*)d_in[10], *be = (const float*)d_in[11];
  const float* Woh = (const float*)d_in[12], *boh = (const float*)d_in[13];
  const float* Woe = (const float*)d_in[14], *boe = (const float*)d_in[15];

  const int n = in_sizes[0] / 64;
  const int E = in_sizes[2];

  float* out = (float*)d_out;
  float* oh = out;                   // n*64 fp32
  float* oe = out + (size_t)n * 64;  // E*64 fp32

  // ws: qb,kb,vbuf (n*64 bf16) | escores (E*8 f32, CSR order) | hout (n*64 f32)
  //   | deg,rowptr,cursor (n int) | blksum (256) | eslot (E) | ecol (E)
  unsigned short* qb   = (unsigned short*)d_ws;
  unsigned short* kb   = qb + (size_t)n * 64;
  unsigned short* vbuf = kb + (size_t)n * 64;
  float* escores = (float*)(vbuf + (size_t)n * 64);
  float* hout    = escores + (size_t)E * 8;

  int* deg    = (int*)(hout + (size_t)n * 64);
  int* rowptr = deg + n;
  int* cursor = rowptr + n;
  int* blksum = cursor + n;
  int* eslot  = blksum + 256;
  int* ecol   = eslot + (size_t)E;

  const int nb_scan = (n + SCAN_B * SCAN_E - 1) / (SCAN_B * SCAN_E);

  // CSR build first (depends only on row/col) so edge_fused can scatter scores.
  zero_kernel<<<(n + 255) / 256, 256, 0, stream>>>(deg, n);
  hist_kernel<<<(E + 255) / 256, 256, 0, stream>>>(row, deg, E);
  scan1_kernel<<<nb_scan, SCAN_B, 0, stream>>>(deg, rowptr, blksum, n);
  scan2_kernel<<<1, SCAN_B, 0, stream>>>(blksum, nb_scan);
  scan3_kernel<<<(n + 255) / 256, 256, 0, stream>>>(rowptr, cursor, blksum, n);
  scatter_kernel<<<(E + 255) / 256, 256, 0, stream>>>(row, col, cursor, eslot, ecol, E);

  qkv3_kernel<<<512, 256, 0, stream>>>(hx, Wq, bq, Wk, bk, Wv, bv, qb, kb, vbuf, n);
  edge_fused_kernel<<<2048, 256, 0, stream>>>(he, row, col, eslot, qb, kb, We, be,
                                              Woe, boe, oe, escores, E);

  row_attn_kernel<<<(n + 3) / 4, 256, 0, stream>>>(escores, rowptr, deg, ecol,
                                                   vbuf, hout, n);
  gemm64_kernel<false, false><<<512, 256, 0, stream>>>(hout, Woh, boh, oh, n);
}